// Round 7
// baseline (24795.285 us; speedup 1.0000x reference)
//
#include <hip/hip_runtime.h>

#define HS   512
#define LNUM 4
#define TT   128
#define MMEM 2048
#define FFD  2048
#define NB   256
#define NT   512
#define INV512 (1.0f/512.0f)
#define QSCALE 0.08838834764831845f  // 1/sqrt(128)

typedef unsigned long long ull;

// ---------------- workspace layout (float offsets; 8B-aligned: all even) ----
constexpr size_t KHALF = (size_t)LNUM*MMEM*HS/2;
constexpr size_t HHALF = (size_t)LNUM*HS*HS/2;
constexpr size_t FHALF = (size_t)LNUM*FFD*HS/2;
constexpr size_t OFF_KBF    = 0;
constexpr size_t OFF_VBF    = OFF_KBF    + KHALF;
constexpr size_t OFF_WCOMBBF= OFF_VBF    + KHALF;
constexpr size_t OFF_WQTBF  = OFF_WCOMBBF+ HHALF;
constexpr size_t OFF_W2TBF  = OFF_WQTBF  + HHALF;
constexpr size_t OFF_FFW1BF = OFF_W2TBF  + FHALF;
constexpr size_t OFF_CAWOBF = OFF_FFW1BF + FHALF;
constexpr size_t OFF_CSA    = OFF_CAWOBF + HHALF;                 // L*HS
constexpr size_t OFF_SQ     = OFF_CSA    + (size_t)LNUM*HS;
constexpr size_t OFF_CBQ    = OFF_SQ     + (size_t)LNUM*HS;
// mutable (memset 0)
constexpr size_t OFF_STATE  = OFF_CBQ    + (size_t)LNUM*HS;
constexpr size_t OFF_H      = OFF_STATE;                          // [2][4][512]
constexpr size_t OFF_C      = OFF_H      + 2*LNUM*HS;             // [2][4][512]
constexpr size_t OFF_Z02    = OFF_C      + 2*LNUM*HS;             // [2][1024] plain
constexpr size_t OFF_Y2P    = OFF_Z02    + 2*2*HS;                // [32][512] plain
constexpr size_t OFF_Z1PW   = OFF_Y2P    + 32*HS;                 // [512] PW
constexpr size_t OFF_XINPW  = OFF_Z1PW   + 2*HS;                  // [512] PW
constexpr size_t OFF_T2PW   = OFF_XINPW  + 2*HS;                  // [512] PW
constexpr size_t OFF_YPW    = OFF_T2PW   + 2*HS;                  // [32][512] PW
constexpr size_t OFF_CTXPW  = OFF_YPW    + 2*32*HS;               // [128][128] PW
constexpr size_t OFF_DENPW  = OFF_CTXPW  + 2*128*128;             // [128] PW
constexpr size_t OFF_S1PW   = OFF_DENPW  + 2*128;                 // [32][2] PW
constexpr size_t OFF_S2PW   = OFF_S1PW   + 2*64;                  // [32][2] PW
constexpr size_t OFF_FLAGS  = OFF_S2PW   + 2*64;                  // NB*32 u32
constexpr size_t WS_TOTAL   = OFF_FLAGS  + (size_t)NB*32;

__device__ __forceinline__ float wred(float v) {
#pragma unroll
  for (int m = 32; m; m >>= 1) v += __shfl_xor(v, m);
  return v;
}
__device__ __forceinline__ float sigm(float x) { return 1.0f/(1.0f+__expf(-x)); }
__device__ __forceinline__ unsigned short f2bf(float f) {
  unsigned u = __float_as_uint(f);
  return (unsigned short)((u + 0x7fffu + ((u >> 16) & 1u)) >> 16);
}
__device__ __forceinline__ float bflo(unsigned v){ return __uint_as_float(v << 16); }
__device__ __forceinline__ float bfhi(unsigned v){ return __uint_as_float(v & 0xffff0000u); }
__device__ __forceinline__ unsigned ldpack(const unsigned short* a, const unsigned short* b){
  return (unsigned)(*a) | ((unsigned)(*b) << 16);
}

__device__ __forceinline__ float ald(const float* p) {
  return __hip_atomic_load(p, __ATOMIC_RELAXED, __HIP_MEMORY_SCOPE_AGENT);
}
__device__ __forceinline__ void ast(float* p, float v) {
  __hip_atomic_store(p, v, __ATOMIC_RELAXED, __HIP_MEMORY_SCOPE_AGENT);
}
__device__ __forceinline__ unsigned aldu(const unsigned* p) {
  return __hip_atomic_load(p, __ATOMIC_RELAXED, __HIP_MEMORY_SCOPE_AGENT);
}
__device__ __forceinline__ void astu(unsigned* p, unsigned v) {
  __hip_atomic_store(p, v, __ATOMIC_RELAXED, __HIP_MEMORY_SCOPE_AGENT);
}
__device__ __forceinline__ ull aldq(const ull* p) {
  return __hip_atomic_load(p, __ATOMIC_RELAXED, __HIP_MEMORY_SCOPE_AGENT);
}
__device__ __forceinline__ void astq(ull* p, ull v) {
  __hip_atomic_store(p, v, __ATOMIC_RELAXED, __HIP_MEMORY_SCOPE_AGENT);
}
// packed word {seq lo32, val hi32}
__device__ __forceinline__ void pwst(ull* p, unsigned seq, float v) {
  astq(p, ((ull)__float_as_uint(v) << 32) | (ull)seq);
}
__device__ __forceinline__ float pwpoll(const ull* p, unsigned seq) {
  ull v = aldq(p);
  while ((unsigned)v != seq) { __builtin_amdgcn_s_sleep(1); v = aldq(p); }
  return __uint_as_float((unsigned)(v >> 32));
}
__device__ __forceinline__ float pwval(const ull* p) {   // barrier-covered read of value half
  return ald((const float*)p + 1);
}
// pipelined poll-sum over N partials (chunk 16 in flight)
template <int N>
__device__ __forceinline__ float pwpollsum(const ull* base, int stride, unsigned seq) {
  constexpr int C = (N < 16) ? N : 16;
  float acc = 0;
  ull v[C];
#pragma unroll
  for (int c = 0; c < N; c += C) {
#pragma unroll
    for (int p = 0; p < C; ++p) v[p] = aldq(base + (size_t)(c+p)*stride);
#pragma unroll
    for (int p = 0; p < C; ++p) {
      while ((unsigned)v[p] != seq) { __builtin_amdgcn_s_sleep(1); v[p] = aldq(base + (size_t)(c+p)*stride); }
      acc += __uint_as_float((unsigned)(v[p] >> 32));
    }
  }
  return acc;
}

// single direct-poll grid barrier; pf overlaps the wait
template <class F>
__device__ __forceinline__ void gridbar(unsigned* flags, unsigned g, F&& pf) {
  asm volatile("s_waitcnt vmcnt(0)" ::: "memory");
  __syncthreads();
  if (threadIdx.x == 0) astu(flags + (size_t)blockIdx.x*32, g);
  pf();
  if (threadIdx.x < NB) {
    const unsigned* f = flags + (size_t)threadIdx.x*32;
    while ((int)(aldu(f) - g) < 0) __builtin_amdgcn_s_sleep(2);
  }
  __syncthreads();
}

// ---------------- precompute kernels (R6, unchanged) ----------------

__global__ __launch_bounds__(256) void kv_gemm(
    const float* __restrict__ hist, const float* __restrict__ caWin,
    const float* __restrict__ caBin, unsigned short* __restrict__ out, int koff) {
  __shared__ float As[16][64];
  __shared__ float Bs[16][64];
  const int l = blockIdx.z, m0 = blockIdx.x*64, f0 = blockIdx.y*64;
  const int tid = threadIdx.x, tm = tid >> 4, tf = tid & 15;
  float acc[4][4] = {};
  for (int e0 = 0; e0 < HS; e0 += 16) {
#pragma unroll
    for (int it = 0; it < 4; ++it) {
      int idx = tid + it*256, k = idx & 15, mm = idx >> 4;
      As[k][mm] = hist[((size_t)(m0+mm)*LNUM + l)*HS + e0 + k];
      Bs[k][mm] = caWin[((size_t)l*(3*HS) + koff + f0 + mm)*HS + e0 + k];
    }
    __syncthreads();
#pragma unroll
    for (int k = 0; k < 16; ++k) {
      float a[4], b[4];
#pragma unroll
      for (int x = 0; x < 4; ++x) { a[x] = As[k][tm*4+x]; b[x] = Bs[k][tf*4+x]; }
#pragma unroll
      for (int x = 0; x < 4; ++x)
#pragma unroll
        for (int y = 0; y < 4; ++y) acc[x][y] += a[x]*b[y];
    }
    __syncthreads();
  }
#pragma unroll
  for (int x = 0; x < 4; ++x)
#pragma unroll
    for (int y = 0; y < 4; ++y) {
      int m = m0 + tm*4 + x, f = f0 + tf*4 + y;
      out[((size_t)l*MMEM + m)*HS + f] = f2bf(acc[x][y] + caBin[l*(3*HS) + koff + f]);
    }
}

__global__ __launch_bounds__(256) void wcomb_gemm(
    const float* __restrict__ saWo, const float* __restrict__ saWin,
    unsigned short* __restrict__ wcomb) {
  __shared__ float As[16][64];
  __shared__ float Bs[16][64];
  const int l = blockIdx.z, f0 = blockIdx.x*64, j0 = blockIdx.y*64;
  const int tid = threadIdx.x, tm = tid >> 4, tf = tid & 15;
  float acc[4][4] = {};
  for (int e0 = 0; e0 < HS; e0 += 16) {
#pragma unroll
    for (int it = 0; it < 4; ++it) {
      int idx = tid + it*256;
      { int k = idx & 15, ff = idx >> 4;
        As[k][ff] = saWo[((size_t)l*HS + f0+ff)*HS + e0 + k]; }
      { int jj = idx & 63, k = idx >> 6;
        Bs[k][jj] = saWin[((size_t)l*(3*HS) + 2*HS + e0 + k)*HS + j0 + jj]; }
    }
    __syncthreads();
#pragma unroll
    for (int k = 0; k < 16; ++k) {
      float a[4], b[4];
#pragma unroll
      for (int x = 0; x < 4; ++x) { a[x] = As[k][tm*4+x]; b[x] = Bs[k][tf*4+x]; }
#pragma unroll
      for (int x = 0; x < 4; ++x)
#pragma unroll
        for (int y = 0; y < 4; ++y) acc[x][y] += a[x]*b[y];
    }
    __syncthreads();
  }
#pragma unroll
  for (int x = 0; x < 4; ++x)
#pragma unroll
    for (int y = 0; y < 4; ++y)
      wcomb[(size_t)l*HS*HS + (size_t)(f0+tm*4+x)*HS + (j0+tf*4+y)] = f2bf(acc[x][y]);
}

__global__ __launch_bounds__(256) void transpose_scale_bf(
    const float* __restrict__ in, size_t inLS, int R, int C,
    const float* __restrict__ g, size_t gLS,
    unsigned short* __restrict__ out, size_t outLS) {
  __shared__ float tile[32][33];
  const int l = blockIdx.z, e0 = blockIdx.x*32, f0 = blockIdx.y*32;
  const int tx = threadIdx.x & 31, ty = threadIdx.x >> 5;
#pragma unroll
  for (int r = 0; r < 32; r += 8)
    tile[ty+r][tx] = in[(size_t)l*inLS + (size_t)(f0+ty+r)*C + e0 + tx];
  __syncthreads();
#pragma unroll
  for (int r = 0; r < 32; r += 8) {
    int e = e0 + ty + r, f = f0 + tx;
    float s = g ? g[(size_t)l*gLS + e] : 1.0f;
    out[(size_t)l*outLS + (size_t)e*R + f] = f2bf(tile[tx][ty+r] * s);
  }
}

__global__ __launch_bounds__(256) void bf16_copy(
    const float* __restrict__ in, unsigned short* __restrict__ out, size_t n) {
  for (size_t i = (size_t)blockIdx.x*256 + threadIdx.x; i < n; i += (size_t)gridDim.x*256)
    out[i] = f2bf(in[i]);
}

__global__ __launch_bounds__(256) void csa_kernel(
    const float* __restrict__ saWo, const float* __restrict__ sabin,
    const float* __restrict__ sabo, float* __restrict__ csa) {
  const int w = threadIdx.x >> 6, lane = threadIdx.x & 63;
  const int row = blockIdx.x*4 + w;
  const int l = row >> 9, f = row & 511;
  float acc = 0;
#pragma unroll
  for (int k = 0; k < 8; ++k) {
    int e = lane + 64*k;
    acc += saWo[((size_t)l*HS + f)*HS + e] * sabin[l*(3*HS) + 2*HS + e];
  }
  acc = wred(acc);
  if (lane == 0) csa[row] = acc + sabo[l*HS + f];
}

__global__ __launch_bounds__(256) void sqcbq_kernel(
    const float* __restrict__ caWin, const float* __restrict__ caBin,
    const float* __restrict__ lnG, const float* __restrict__ lnB,
    float* __restrict__ sq, float* __restrict__ cbq) {
  const int w = threadIdx.x >> 6, lane = threadIdx.x & 63;
  const int row = blockIdx.x*4 + w;
  const int l = row >> 9, f = row & 511;
  float a1 = 0, a2 = 0;
#pragma unroll
  for (int k = 0; k < 8; ++k) {
    int e = lane + 64*k;
    float wv = caWin[((size_t)l*(3*HS) + f)*HS + e];
    a1 += wv * lnG[l*(3*HS) + e];
    a2 += wv * lnB[l*(3*HS) + e];
  }
  a1 = wred(a1); a2 = wred(a2);
  if (lane == 0) { sq[row] = a1; cbq[row] = a2 + caBin[l*(3*HS) + f]; }
}

// ---------------- main persistent sequential kernel ----------------

__global__ __launch_bounds__(NT, 2) void seq_kernel(
    const float* __restrict__ x,
    const float* __restrict__ Wx,  const float* __restrict__ bx,
    const float* __restrict__ Wh,  const float* __restrict__ bh,
    const float* __restrict__ caBo,
    const float* __restrict__ ffB1,
    const float* __restrict__ ffB2,
    const float* __restrict__ lnG,  const float* __restrict__ lnB,
    float* __restrict__ ws, float* __restrict__ out) {
  const unsigned short* Kb    = (const unsigned short*)(ws + OFF_KBF);
  const unsigned short* Vb    = (const unsigned short*)(ws + OFF_VBF);
  const unsigned short* Wcomb = (const unsigned short*)(ws + OFF_WCOMBBF);
  const unsigned short* WqT   = (const unsigned short*)(ws + OFF_WQTBF);
  const unsigned short* W2T   = (const unsigned short*)(ws + OFF_W2TBF);
  const unsigned short* F1b   = (const unsigned short*)(ws + OFF_FFW1BF);
  const unsigned short* CaWob = (const unsigned short*)(ws + OFF_CAWOBF);
  const float* csag  = ws + OFF_CSA;
  const float* sqg   = ws + OFF_SQ;
  const float* cbqg  = ws + OFF_CBQ;
  float* hG    = ws + OFF_H;
  float* cG    = ws + OFF_C;
  float* z02g  = ws + OFF_Z02;
  float* Y2P   = ws + OFF_Y2P;
  ull* Z1PW   = (ull*)(ws + OFF_Z1PW);
  ull* XINPW  = (ull*)(ws + OFF_XINPW);
  ull* T2PW   = (ull*)(ws + OFF_T2PW);
  ull* YPW    = (ull*)(ws + OFF_YPW);
  ull* CTXPW  = (ull*)(ws + OFF_CTXPW);
  ull* DENPW  = (ull*)(ws + OFF_DENPW);
  ull* S1PW   = (ull*)(ws + OFF_S1PW);
  ull* S2PW   = (ull*)(ws + OFF_S2PW);
  unsigned* bflags = (unsigned*)(ws + OFF_FLAGS);

  __shared__ float sh_xin[HS], sh_h[HS], sh_vec[HS];
  __shared__ float sh_aux[64], sh_q[128], sh_p[64], sh_t1[16];
  __shared__ float sh_red[24], sh_den[4];

  const int bid = blockIdx.x, tid = threadIdx.x;
  const int w = tid >> 6, lane = tid & 63;
  const bool isZ = bid < 64;
  const bool isT = bid >= 64 && bid < 96;
  const bool isA = bid >= 96 && bid < 224;

  // prefetch register union: ph (packed bf16 pairs), pf32 (f32 gate rows)
  unsigned ph[64];
  float pf32[16];

  auto pfrole = [&](int l) {
    if (isZ) {
      const float* wxr = Wx + (((size_t)l*3 + 1)*HS + bid*8 + w)*HS;
      const float* whr = Wh + (((size_t)l*3 + 1)*HS + bid*8 + w)*HS;
#pragma unroll
      for (int k = 0; k < 8; ++k) { pf32[k] = wxr[lane+64*k]; pf32[8+k] = whr[lane+64*k]; }
    } else if (isT) {
      const int b = bid - 64;
#pragma unroll
      for (int rr = 0; rr < 2; ++rr) {
        const unsigned short* base = Wcomb + ((size_t)l*HS + b*16 + w*2 + rr)*HS;
        const unsigned short* cbase = CaWob + ((size_t)l*HS + b*16 + w*2 + rr)*HS;
#pragma unroll
        for (int kk = 0; kk < 4; ++kk) {
          ph[rr*4+kk]    = ldpack(base + lane + 128*kk,  base + lane + 64 + 128*kk);
          ph[16+rr*4+kk] = ldpack(cbase + lane + 128*kk, cbase + lane + 64 + 128*kk);
        }
      }
#pragma unroll
      for (int q = 0; q < 8; ++q)
        ph[8+q] = ldpack(WqT + ((size_t)l*HS + b*16 + 2*q)*HS + tid,
                         WqT + ((size_t)l*HS + b*16 + 2*q+1)*HS + tid);
    } else if (isA) {
      const int b2 = bid - 96, h = b2 >> 5, ms = b2 & 31;
      const int g4 = tid >> 7, dd = tid & 127;
#pragma unroll
      for (int rr = 0; rr < 8; ++rr) {
        const unsigned short* kr = Kb + ((size_t)l*MMEM + ms*64 + w*8 + rr)*HS + h*128;
        ph[rr] = ldpack(kr + lane, kr + lane + 64);
      }
#pragma unroll
      for (int q = 0; q < 8; ++q)
        ph[8+q] = ldpack(Vb + ((size_t)l*MMEM + ms*64 + g4*16 + 2*q)*HS + h*128 + dd,
                         Vb + ((size_t)l*MMEM + ms*64 + g4*16 + 2*q+1)*HS + h*128 + dd);
      const int rowid = b2*8 + w, g = (rowid < 512) ? 0 : 2, f = rowid & 511;
      const float* wxr = Wx + (((size_t)l*3 + g)*HS + f)*HS;
      const float* whr = Wh + (((size_t)l*3 + g)*HS + f)*HS;
#pragma unroll
      for (int k = 0; k < 8; ++k) { pf32[k] = wxr[lane+64*k]; pf32[8+k] = whr[lane+64*k]; }
    } else {
      const int fb = bid - 224;
#pragma unroll
      for (int q = 0; q < 8; ++q) {
        const unsigned short* base = F1b + ((size_t)l*FFD + fb*64 + w*8 + q)*HS;
#pragma unroll
        for (int kk = 0; kk < 4; ++kk)
          ph[q*4+kk] = ldpack(base + lane + 128*kk, base + lane + 64 + 128*kk);
      }
#pragma unroll
      for (int q = 0; q < 32; ++q)
        ph[32+q] = ldpack(W2T + ((size_t)l*FFD + fb*64 + 2*q)*HS + tid,
                          W2T + ((size_t)l*FFD + fb*64 + 2*q+1)*HS + tid);
    }
  };

  // fused LSTM update for step s-1 (Z-blocks; all inputs barrier-covered)
  auto do_update = [&](int ip, int parp, int parz, float& xn, float& cn) {
    const int j = tid;
    float t2v = pwval(T2PW + j);
    float z0  = ald(z02g + parz*1024 + j);
    float z2  = ald(z02g + parz*1024 + HS + j);
    float y2 = 0;
    {
      float yv[16];
#pragma unroll
      for (int c = 0; c < 32; c += 16) {
#pragma unroll
        for (int p = 0; p < 16; ++p) yv[p] = ald(Y2P + (size_t)(c+p)*HS + j);
#pragma unroll
        for (int p = 0; p < 16; ++p) y2 += yv[p];
      }
    }
    if (w == 0) {
      float a = (lane < 32) ? pwval(S2PW + lane*2) : pwval(S2PW + (lane-32)*2 + 1);
#pragma unroll
      for (int m = 16; m; m >>= 1) a += __shfl_xor(a, m);
      if (lane == 0)  sh_red[16] = a;
      if (lane == 32) sh_red[17] = a;
    }
    __syncthreads();
    float m2 = sh_red[16]*INV512;
    float r2 = rsqrtf(sh_red[17]*INV512 - m2*m2 + 1e-5f);
    float x2 = (t2v-m2)*r2*lnG[(ip*3+1)*HS+j] + lnB[(ip*3+1)*HS+j];
    float t3 = x2 + y2 + ffB2[ip*HS + j];
    float s_ = t3, q_ = t3*t3;
#pragma unroll
    for (int m = 32; m; m >>= 1) { s_ += __shfl_xor(s_, m); q_ += __shfl_xor(q_, m); }
    if (lane == 0) { sh_red[w] = s_; sh_red[8+w] = q_; }
    __syncthreads();
    if (tid == 0) {
      float a = 0, b = 0;
#pragma unroll
      for (int k = 0; k < 8; ++k) { a += sh_red[k]; b += sh_red[8+k]; }
      sh_red[0] = a; sh_red[1] = b;
    }
    __syncthreads();
    float m3 = sh_red[0]*INV512;
    float r3 = rsqrtf(sh_red[1]*INV512 - m3*m3 + 1e-5f);
    float d  = (t3-m3)*r3*lnG[(ip*3+2)*HS+j] + lnB[(ip*3+2)*HS+j];
    float cp = ald(cG + (parp*LNUM + ip)*HS + j);
    float ft = sigm(cp - d);
    float it = sigm(z0);
    float gt = tanhf(z2);
    cn = ft*cp + it*gt;
    xn = tanhf(cn);
  };

  pfrole(0);

  for (int s = 0; s < TT*LNUM; ++s) {
    const int t = s >> 2, i = s & 3;
    const int par = t & 1;
    const unsigned sq = (unsigned)(s + 1);

    if (isZ) {
      // ---- update(s-1) + z1 matvec ----
      float xn = 0.f, cn = 0.f;
      if (s > 0 && (bid == 0 || i > 0)) {
        const int ip = (s-1) & 3, tp = (s-1) >> 2, parp = tp & 1;
        do_update(ip, parp, (s-1) & 1, xn, cn);
        if (bid == 0) {
          ast(hG + ((parp^1)*LNUM + ip)*HS + tid, xn);
          ast(cG + ((parp^1)*LNUM + ip)*HS + tid, cn);
          if (ip == 3) out[tp*HS + tid] = xn;
        }
      }
      float xv = (i == 0) ? x[t*HS + tid] : xn;
      if (bid == 0) pwst(XINPW + tid, sq, xv);
      sh_xin[tid] = xv;
      sh_h[tid]   = ald(hG + (par*LNUM + i)*HS + tid);
      __syncthreads();
      const int f = bid*8 + w;
      float acc = 0;
#pragma unroll
      for (int k = 0; k < 8; ++k) {
        int e = lane + 64*k;
        acc += pf32[k]*sh_xin[e] + pf32[8+k]*sh_h[e];
      }
      acc = wred(acc);
      if (lane == 0) pwst(Z1PW + f, sq, acc + bx[(i*3+1)*HS + f] + bh[(i*3+1)*HS + f]);
    } else if (isT) {
      const int b = bid - 64;
      // ---- t1: poll z1 ----
      sh_vec[tid] = sigm(pwpoll(Z1PW + tid, sq));
      __syncthreads();
#pragma unroll
      for (int rr = 0; rr < 2; ++rr) {
        const int j = b*16 + w*2 + rr;
        float acc = 0;
#pragma unroll
        for (int kk = 0; kk < 4; ++kk) {
          unsigned pw = ph[rr*4+kk];
          acc += bflo(pw)*sh_vec[lane+128*kk] + bfhi(pw)*sh_vec[lane+64+128*kk];
        }
        acc = wred(acc);
        if (lane == 0) sh_t1[w*2+rr] = sh_vec[j] + acc + csag[i*HS + j];
      }
      __syncthreads();
      // ---- Y partial + s1 slots ----
      {
        float yl = 0;
#pragma unroll
        for (int q = 0; q < 8; ++q) {
          unsigned pw = ph[8+q];
          yl += sh_t1[2*q]*bflo(pw) + sh_t1[2*q+1]*bfhi(pw);
        }
        pwst(YPW + (size_t)b*512 + tid, sq, yl);
      }
      if (w == 0 && lane < 16) {
        float v = sh_t1[lane], s_ = v, q_ = v*v;
#pragma unroll
        for (int m = 8; m; m >>= 1) { s_ += __shfl_xor(s_, m); q_ += __shfl_xor(q_, m); }
        if (lane == 0) { pwst(S1PW + b*2, sq, s_); pwst(S1PW + b*2 + 1, sq, q_); }
      }
      // ---- t2: poll ctx partials + den + s1 ----
      const int hh = tid >> 7, dd = tid & 127;
      float ctxa = pwpollsum<32>(CTXPW + (size_t)hh*4096 + dd, 128, sq);
      if (tid < 128) sh_q[tid] = pwpoll(DENPW + tid, sq);
      if (w == 0) {
        float a = (lane < 32) ? pwpoll(S1PW + lane*2, sq) : pwpoll(S1PW + (lane-32)*2 + 1, sq);
#pragma unroll
        for (int m = 16; m; m >>= 1) a += __shfl_xor(a, m);
        if (lane == 0)  sh_red[18] = a;
        if (lane == 32) sh_red[19] = a;
      }
      __syncthreads();
      if (w >= 4) {
        int h2 = w - 4;
        if (lane < 32) {
          float v = sh_q[h2*32 + lane];
#pragma unroll
          for (int m = 16; m; m >>= 1) v += __shfl_xor(v, m);
          if (lane == 0) sh_den[h2] = v;
        }
      }
      __syncthreads();
      sh_vec[tid] = ctxa / sh_den[hh];
      __syncthreads();
      const float m1 = sh_red[18]*INV512;
      const float r1 = rsqrtf(sh_red[19]*INV512 - m1*m1 + 1e-5f);
#pragma unroll
      for (int rr = 0; rr < 2; ++rr) {
        const int r = w*2 + rr, j = b*16 + r;
        float a2 = 0;
#pragma unroll
        for (int kk = 0; kk < 4; ++kk) {
          unsigned pw = ph[16+rr*4+kk];
          a2 += bflo(pw)*sh_vec[lane+128*kk] + bfhi(pw)*sh_vec[lane+64+128*kk];
        }
        a2 = wred(a2);
        if (lane == 0) {
          float x1 = (sh_t1[r]-m1)*r1*lnG[(i*3)*HS + j] + lnB[(i*3)*HS + j];
          float t2v = x1 + a2 + caBo[i*HS + j];
          pwst(T2PW + j, sq, t2v);
          sh_aux[r] = t2v;
        }
      }
      __syncthreads();
      if (w == 0 && lane < 16) {
        float v = sh_aux[lane], s_ = v, q_ = v*v;
#pragma unroll
        for (int m = 8; m; m >>= 1) { s_ += __shfl_xor(s_, m); q_ += __shfl_xor(q_, m); }
        if (lane == 0) { pwst(S2PW + b*2, sq, s_); pwst(S2PW + b*2 + 1, sq, q_); }
      }
    } else if (isA) {
      const int b2 = bid - 96, h = b2 >> 5;
      const int g4 = tid >> 7, dd = tid & 127;
      // ---- q: poll Y partials (8 per thread-group) + s1 ----
      sh_vec[tid] = pwpollsum<8>(YPW + (size_t)(g4*8)*512 + h*128 + dd, 512, sq);
      if (w == 0) {
        float a = (lane < 32) ? pwpoll(S1PW + lane*2, sq) : pwpoll(S1PW + (lane-32)*2 + 1, sq);
#pragma unroll
        for (int m = 16; m; m >>= 1) a += __shfl_xor(a, m);
        if (lane == 0)  sh_red[18] = a;
        if (lane == 32) sh_red[19] = a;
      }
      __syncthreads();
      if (tid < 128) {
        float Ysum = sh_vec[tid] + sh_vec[128+tid] + sh_vec[256+tid] + sh_vec[384+tid];
        float m1 = sh_red[18]*INV512;
        float r1 = rsqrtf(sh_red[19]*INV512 - m1*m1 + 1e-5f);
        int f = h*128 + tid;
        sh_q[tid] = r1*(Ysum - m1*sqg[i*HS + f]) + cbqg[i*HS + f];
      }
      __syncthreads();
      // ---- scores + exp ----
#pragma unroll
      for (int rr = 0; rr < 8; ++rr) {
        unsigned pw = ph[rr];
        float sc = sh_q[lane]*bflo(pw) + sh_q[lane+64]*bfhi(pw);
        sc = wred(sc);
        if (lane == 0) sh_p[w*8+rr] = __expf(sc * QSCALE);
      }
      __syncthreads();
      // ---- ctx partial + den ----
      {
        float acc = 0;
#pragma unroll
        for (int q = 0; q < 8; ++q) {
          unsigned pw = ph[8+q];
          acc += sh_p[g4*16 + 2*q]*bflo(pw) + sh_p[g4*16 + 2*q+1]*bfhi(pw);
        }
        sh_vec[tid] = acc;
      }
      if (w == 0) {
        float v = wred(sh_p[lane]);
        if (lane == 0) pwst(DENPW + b2, sq, v);
      }
      __syncthreads();
      if (tid < 128) {
        float tot = sh_vec[tid] + sh_vec[128+tid] + sh_vec[256+tid] + sh_vec[384+tid];
        pwst(CTXPW + (size_t)b2*128 + tid, sq, tot);
      }
      // ---- z0/z2 matvec (consumed next window) ----
      float xv = pwpoll(XINPW + tid, sq);
      sh_xin[tid] = xv;
      sh_h[tid]   = ald(hG + (par*LNUM + i)*HS + tid);
      __syncthreads();
      {
        const int rowid = b2*8 + w, g = (rowid < 512) ? 0 : 2, f = rowid & 511;
        float acc = 0;
#pragma unroll
        for (int k = 0; k < 8; ++k) {
          int e = lane + 64*k;
          acc += pf32[k]*sh_xin[e] + pf32[8+k]*sh_h[e];
        }
        acc = wred(acc);
        if (lane == 0)
          ast(z02g + (s & 1)*1024 + (g ? HS : 0) + f,
              acc + bx[(i*3+g)*HS + f] + bh[(i*3+g)*HS + f]);
      }
    } else {
      const int fb = bid - 224;
      // ---- ff: poll t2 + s2 ----
      float t2v = pwpoll(T2PW + tid, sq);
      if (w == 0) {
        float a = (lane < 32) ? pwpoll(S2PW + lane*2, sq) : pwpoll(S2PW + (lane-32)*2 + 1, sq);
#pragma unroll
        for (int m = 16; m; m >>= 1) a += __shfl_xor(a, m);
        if (lane == 0)  sh_red[16] = a;
        if (lane == 32) sh_red[17] = a;
      }
      __syncthreads();
      const float m2 = sh_red[16]*INV512;
      const float r2 = rsqrtf(sh_red[17]*INV512 - m2*m2 + 1e-5f);
      sh_vec[tid] = (t2v-m2)*r2*lnG[(i*3+1)*HS + tid] + lnB[(i*3+1)*HS + tid];
      __syncthreads();
#pragma unroll
      for (int q = 0; q < 8; ++q) {
        const int r = w*8 + q;
        float acc = 0;
#pragma unroll
        for (int kk = 0; kk < 4; ++kk) {
          unsigned pw = ph[q*4+kk];
          acc += bflo(pw)*sh_vec[lane+128*kk] + bfhi(pw)*sh_vec[lane+64+128*kk];
        }
        acc = wred(acc);
        if (lane == 0) sh_aux[r] = fmaxf(acc + ffB1[i*FFD + fb*64 + r], 0.f);
      }
      __syncthreads();
      {
        float yl = 0;
#pragma unroll
        for (int q = 0; q < 32; ++q) {
          unsigned pw = ph[32+q];
          yl += sh_aux[2*q]*bflo(pw) + sh_aux[2*q+1]*bfhi(pw);
        }
        ast(Y2P + (size_t)fb*HS + tid, yl);
      }
    }
    gridbar(bflags, sq, [&]{ pfrole((s+1) & 3); });
  }

  // ---------- epilogue: final update (t=127, i=3) + output assembly ----------
  if (bid == 0) {
    float xn, cn;
    do_update(3, 1, 1, xn, cn);
    out[127*HS + tid] = xn;
    out[TT*HS + 3*HS + tid] = xn;                 // h_T[3]
    out[TT*HS + LNUM*HS + 3*HS + tid] = cn;       // c_T[3]
#pragma unroll
    for (int ii = 0; ii < 3; ++ii) {
      out[TT*HS + ii*HS + tid]            = ald(hG + (0*LNUM + ii)*HS + tid);
      out[TT*HS + LNUM*HS + ii*HS + tid]  = ald(cG + (0*LNUM + ii)*HS + tid);
    }
  }
}

// ---------------- host launcher ----------------
extern "C" void kernel_launch(void* const* d_in, const int* in_sizes, int n_in,
                              void* d_out, int out_size, void* d_ws, size_t ws_size,
                              hipStream_t stream) {
  const float* x      = (const float*)d_in[0];
  const float* hist   = (const float*)d_in[1];
  const float* Wx     = (const float*)d_in[2];
  const float* bx     = (const float*)d_in[3];
  const float* Wh     = (const float*)d_in[4];
  const float* bh     = (const float*)d_in[5];
  const float* saWin  = (const float*)d_in[6];
  const float* saBin  = (const float*)d_in[7];
  const float* saWo   = (const float*)d_in[8];
  const float* saBo   = (const float*)d_in[9];
  const float* caWin  = (const float*)d_in[10];
  const float* caBin  = (const float*)d_in[11];
  const float* caWo   = (const float*)d_in[12];
  const float* caBo   = (const float*)d_in[13];
  const float* ffW1   = (const float*)d_in[14];
  const float* ffB1   = (const float*)d_in[15];
  const float* ffW2   = (const float*)d_in[16];
  const float* ffB2   = (const float*)d_in[17];
  const float* lnG    = (const float*)d_in[18];
  const float* lnB    = (const float*)d_in[19];
  float* ws  = (float*)d_ws;
  float* out = (float*)d_out;

  hipMemsetAsync((char*)d_ws + OFF_STATE*sizeof(float), 0,
                 (WS_TOTAL - OFF_STATE)*sizeof(float), stream);

  kv_gemm<<<dim3(MMEM/64, HS/64, LNUM), 256, 0, stream>>>(
      hist, caWin, caBin, (unsigned short*)(ws + OFF_KBF), HS);
  kv_gemm<<<dim3(MMEM/64, HS/64, LNUM), 256, 0, stream>>>(
      hist, caWin, caBin, (unsigned short*)(ws + OFF_VBF), 2*HS);
  wcomb_gemm<<<dim3(HS/64, HS/64, LNUM), 256, 0, stream>>>(
      saWo, saWin, (unsigned short*)(ws + OFF_WCOMBBF));
  csa_kernel<<<(LNUM*HS)/4, 256, 0, stream>>>(saWo, saBin, saBo, ws + OFF_CSA);
  transpose_scale_bf<<<dim3(HS/32, HS/32, LNUM), 256, 0, stream>>>(
      caWin, (size_t)(3*HS)*HS, HS, HS, lnG, (size_t)(3*HS),
      (unsigned short*)(ws + OFF_WQTBF), (size_t)HS*HS);
  sqcbq_kernel<<<(LNUM*HS)/4, 256, 0, stream>>>(caWin, caBin, lnG, lnB, ws + OFF_SQ, ws + OFF_CBQ);
  transpose_scale_bf<<<dim3(FFD/32, HS/32, LNUM), 256, 0, stream>>>(
      ffW2, (size_t)HS*FFD, HS, FFD, nullptr, 0,
      (unsigned short*)(ws + OFF_W2TBF), (size_t)FFD*HS);
  bf16_copy<<<2048, 256, 0, stream>>>(ffW1, (unsigned short*)(ws + OFF_FFW1BF),
                                      (size_t)LNUM*FFD*HS);
  bf16_copy<<<1024, 256, 0, stream>>>(caWo, (unsigned short*)(ws + OFF_CAWOBF),
                                      (size_t)LNUM*HS*HS);

  seq_kernel<<<NB, NT, 0, stream>>>(x, Wx, bx, Wh, bh, caBo,
                                    ffB1, ffB2, lnG, lnB, ws, out);
}

// Round 8
// 23949.327 us; speedup vs baseline: 1.0353x; 1.0353x over previous
//
#include <hip/hip_runtime.h>

#define HS   512
#define LNUM 4
#define TT   128
#define MMEM 2048
#define FFD  2048
#define NB   256
#define NT   512
#define INV512 (1.0f/512.0f)
#define QSCALE 0.08838834764831845f  // 1/sqrt(128)

typedef unsigned long long ull;

// ---------------- workspace layout (float offsets; all even => 8B aligned) --
constexpr size_t KHALF = (size_t)LNUM*MMEM*HS/2;
constexpr size_t HHALF = (size_t)LNUM*HS*HS/2;
constexpr size_t FHALF = (size_t)LNUM*FFD*HS/2;
constexpr size_t OFF_KBF    = 0;
constexpr size_t OFF_VBF    = OFF_KBF    + KHALF;
constexpr size_t OFF_WCOMBBF= OFF_VBF    + KHALF;
constexpr size_t OFF_WQTBF  = OFF_WCOMBBF+ HHALF;
constexpr size_t OFF_CAWOBF = OFF_WQTBF  + HHALF;
constexpr size_t OFF_W2TBF  = OFF_CAWOBF + HHALF;
constexpr size_t OFF_FFW1BF = OFF_W2TBF  + FHALF;
constexpr size_t OFF_WGCBF  = OFF_FFW1BF + FHALF;
constexpr size_t OFF_CSA    = OFF_WGCBF  + FHALF;                 // L*HS
constexpr size_t OFF_SQ     = OFF_CSA    + (size_t)LNUM*HS;
constexpr size_t OFF_CBQ    = OFF_SQ     + (size_t)LNUM*HS;
constexpr size_t OFF_SU     = OFF_CBQ    + (size_t)LNUM*HS;       // L*FF
constexpr size_t OFF_CF1    = OFF_SU     + (size_t)LNUM*FFD;
constexpr size_t OFF_CF2    = OFF_CF1    + (size_t)LNUM*FFD;
// mutable (memset 0)
constexpr size_t OFF_STATE  = OFF_CF2    + (size_t)LNUM*FFD;
constexpr size_t OFF_H      = OFF_STATE;                          // [2][4][512]
constexpr size_t OFF_C      = OFF_H      + 2*LNUM*HS;
constexpr size_t OFF_XING   = OFF_C      + 2*LNUM*HS;             // 512
constexpr size_t OFF_Z1G    = OFF_XING   + HS;                    // 512
constexpr size_t OFF_Z02G   = OFF_Z1G    + HS;                    // 1024
constexpr size_t OFF_T1G    = OFF_Z02G   + 2*HS;                  // 512
constexpr size_t OFF_T2G    = OFF_T1G    + HS;                    // 512
constexpr size_t OFF_YP     = OFF_T2G    + HS;                    // [32][512]
constexpr size_t OFF_CTXP   = OFF_YP     + 32*HS;                 // [128][128]
constexpr size_t OFF_Y2P    = OFF_CTXP   + 128*128;               // [32][512]
constexpr size_t OFF_DENS   = OFF_Y2P    + 32*HS;                 // 128
constexpr size_t OFF_S1S    = OFF_DENS   + 128;                   // 64
constexpr size_t OFF_S2PW   = OFF_S1S    + 64;                    // 64 ull = 128 f
constexpr size_t OFF_J1     = OFF_S2PW   + 128;                   // 64*32 u32
constexpr size_t OFF_JT     = OFF_J1     + 64*32;                 // 32*32 u32
constexpr size_t OFF_J2     = OFF_JT     + 32*32;                 // 128*32 u32
constexpr size_t OFF_FLAGS  = OFF_J2     + 128*32;                // NB*32 u32
constexpr size_t WS_TOTAL   = OFF_FLAGS  + (size_t)NB*32;

__device__ __forceinline__ float wred(float v) {
#pragma unroll
  for (int m = 32; m; m >>= 1) v += __shfl_xor(v, m);
  return v;
}
__device__ __forceinline__ float sigm(float x) { return 1.0f/(1.0f+__expf(-x)); }
__device__ __forceinline__ unsigned short f2bf(float f) {
  unsigned u = __float_as_uint(f);
  return (unsigned short)((u + 0x7fffu + ((u >> 16) & 1u)) >> 16);
}
__device__ __forceinline__ float bflo(unsigned v){ return __uint_as_float(v << 16); }
__device__ __forceinline__ float bfhi(unsigned v){ return __uint_as_float(v & 0xffff0000u); }
__device__ __forceinline__ unsigned ldpack(const unsigned short* a, const unsigned short* b){
  return (unsigned)(*a) | ((unsigned)(*b) << 16);
}

__device__ __forceinline__ float ald(const float* p) {
  return __hip_atomic_load(p, __ATOMIC_RELAXED, __HIP_MEMORY_SCOPE_AGENT);
}
__device__ __forceinline__ void ast(float* p, float v) {
  __hip_atomic_store(p, v, __ATOMIC_RELAXED, __HIP_MEMORY_SCOPE_AGENT);
}
__device__ __forceinline__ unsigned aldu(const unsigned* p) {
  return __hip_atomic_load(p, __ATOMIC_RELAXED, __HIP_MEMORY_SCOPE_AGENT);
}
__device__ __forceinline__ void astu(unsigned* p, unsigned v) {
  __hip_atomic_store(p, v, __ATOMIC_RELAXED, __HIP_MEMORY_SCOPE_AGENT);
}
__device__ __forceinline__ ull aldq(const ull* p) {
  return __hip_atomic_load(p, __ATOMIC_RELAXED, __HIP_MEMORY_SCOPE_AGENT);
}
__device__ __forceinline__ void astq(ull* p, ull v) {
  __hip_atomic_store(p, v, __ATOMIC_RELAXED, __HIP_MEMORY_SCOPE_AGENT);
}
__device__ __forceinline__ void pwst(ull* p, unsigned seq, float v) {
  astq(p, ((ull)__float_as_uint(v) << 32) | (ull)seq);
}
__device__ __forceinline__ float pwpoll(const ull* p, unsigned seq) {
  ull v = aldq(p);
  while ((unsigned)v != seq) { __builtin_amdgcn_s_sleep(1); v = aldq(p); }
  return __uint_as_float((unsigned)(v >> 32));
}
__device__ __forceinline__ float pwval(const ull* p) {   // barrier-covered value read
  return ald((const float*)p + 1);
}

// direct-poll grid barrier; pf overlaps the wait
template <class F>
__device__ __forceinline__ void gridbar(unsigned* flags, unsigned g, F&& pf) {
  asm volatile("s_waitcnt vmcnt(0)" ::: "memory");
  __syncthreads();
  if (threadIdx.x == 0) astu(flags + (size_t)blockIdx.x*32, g);
  pf();
  if (threadIdx.x < NB) {
    const unsigned* f = flags + (size_t)threadIdx.x*32;
    while ((int)(aldu(f) - g) < 0) __builtin_amdgcn_s_sleep(2);
  }
  __syncthreads();
}

// narrow join: producer sets own flag after draining stores
__device__ __forceinline__ void jflag(unsigned* J, int id, unsigned val) {
  asm volatile("s_waitcnt vmcnt(0)" ::: "memory");
  __syncthreads();
  if (threadIdx.x == 0) astu(J + (size_t)id*32, val);
}
__device__ __forceinline__ void jwait(unsigned* J, int n, unsigned val) {
  if (threadIdx.x < n) {
    const unsigned* f = J + (size_t)threadIdx.x*32;
    while ((int)(aldu(f) - val) < 0) __builtin_amdgcn_s_sleep(1);
  }
  __syncthreads();
}

// warp0: reduce 32 (sum,sumsq) f32 slot pairs -> sh[o], sh[o+1]
__device__ __forceinline__ void slotred32(const float* slots, float* sh, int o,
                                          int w, int lane) {
  if (w == 0) {
    float a = (lane < 32) ? ald(slots + lane*2) : ald(slots + (lane-32)*2 + 1);
#pragma unroll
    for (int m = 16; m; m >>= 1) a += __shfl_xor(a, m);
    if (lane == 0)  sh[o]   = a;
    if (lane == 32) sh[o+1] = a;
  }
}

// ---------------- precompute kernels ----------------

__global__ __launch_bounds__(256) void kv_gemm(
    const float* __restrict__ hist, const float* __restrict__ caWin,
    const float* __restrict__ caBin, unsigned short* __restrict__ out, int koff) {
  __shared__ float As[16][64];
  __shared__ float Bs[16][64];
  const int l = blockIdx.z, m0 = blockIdx.x*64, f0 = blockIdx.y*64;
  const int tid = threadIdx.x, tm = tid >> 4, tf = tid & 15;
  float acc[4][4] = {};
  for (int e0 = 0; e0 < HS; e0 += 16) {
#pragma unroll
    for (int it = 0; it < 4; ++it) {
      int idx = tid + it*256, k = idx & 15, mm = idx >> 4;
      As[k][mm] = hist[((size_t)(m0+mm)*LNUM + l)*HS + e0 + k];
      Bs[k][mm] = caWin[((size_t)l*(3*HS) + koff + f0 + mm)*HS + e0 + k];
    }
    __syncthreads();
#pragma unroll
    for (int k = 0; k < 16; ++k) {
      float a[4], b[4];
#pragma unroll
      for (int x = 0; x < 4; ++x) { a[x] = As[k][tm*4+x]; b[x] = Bs[k][tf*4+x]; }
#pragma unroll
      for (int x = 0; x < 4; ++x)
#pragma unroll
        for (int y = 0; y < 4; ++y) acc[x][y] += a[x]*b[y];
    }
    __syncthreads();
  }
#pragma unroll
  for (int x = 0; x < 4; ++x)
#pragma unroll
    for (int y = 0; y < 4; ++y) {
      int m = m0 + tm*4 + x, f = f0 + tf*4 + y;
      out[((size_t)l*MMEM + m)*HS + f] = f2bf(acc[x][y] + caBin[l*(3*HS) + koff + f]);
    }
}

__global__ __launch_bounds__(256) void wcomb_gemm(
    const float* __restrict__ saWo, const float* __restrict__ saWin,
    unsigned short* __restrict__ wcomb) {
  __shared__ float As[16][64];
  __shared__ float Bs[16][64];
  const int l = blockIdx.z, f0 = blockIdx.x*64, j0 = blockIdx.y*64;
  const int tid = threadIdx.x, tm = tid >> 4, tf = tid & 15;
  float acc[4][4] = {};
  for (int e0 = 0; e0 < HS; e0 += 16) {
#pragma unroll
    for (int it = 0; it < 4; ++it) {
      int idx = tid + it*256;
      { int k = idx & 15, ff = idx >> 4;
        As[k][ff] = saWo[((size_t)l*HS + f0+ff)*HS + e0 + k]; }
      { int jj = idx & 63, k = idx >> 6;
        Bs[k][jj] = saWin[((size_t)l*(3*HS) + 2*HS + e0 + k)*HS + j0 + jj]; }
    }
    __syncthreads();
#pragma unroll
    for (int k = 0; k < 16; ++k) {
      float a[4], b[4];
#pragma unroll
      for (int x = 0; x < 4; ++x) { a[x] = As[k][tm*4+x]; b[x] = Bs[k][tf*4+x]; }
#pragma unroll
      for (int x = 0; x < 4; ++x)
#pragma unroll
        for (int y = 0; y < 4; ++y) acc[x][y] += a[x]*b[y];
    }
    __syncthreads();
  }
#pragma unroll
  for (int x = 0; x < 4; ++x)
#pragma unroll
    for (int y = 0; y < 4; ++y)
      wcomb[(size_t)l*HS*HS + (size_t)(f0+tm*4+x)*HS + (j0+tf*4+y)] = f2bf(acc[x][y]);
}

// WGC[l,k,j] = sum_e ffW1[l,k,e]*g2[l,e]*caWo[l,e,j]  (bf16 out)
__global__ __launch_bounds__(256) void wgc_gemm(
    const float* __restrict__ ffW1, const float* __restrict__ lnG,
    const float* __restrict__ caWo, unsigned short* __restrict__ wgc) {
  __shared__ float As[16][64];
  __shared__ float Bs[16][64];
  const int l = blockIdx.z, f0 = blockIdx.x*64, j0 = blockIdx.y*64;
  const int tid = threadIdx.x, tm = tid >> 4, tf = tid & 15;
  float acc[4][4] = {};
  for (int e0 = 0; e0 < HS; e0 += 16) {
#pragma unroll
    for (int it = 0; it < 4; ++it) {
      int idx = tid + it*256;
      { int k = idx & 15, ff = idx >> 4;
        As[k][ff] = ffW1[((size_t)l*FFD + f0+ff)*HS + e0 + k] * lnG[l*(3*HS) + HS + e0 + k]; }
      { int jj = idx & 63, k = idx >> 6;
        Bs[k][jj] = caWo[((size_t)l*HS + e0 + k)*HS + j0 + jj]; }
    }
    __syncthreads();
#pragma unroll
    for (int k = 0; k < 16; ++k) {
      float a[4], b[4];
#pragma unroll
      for (int x = 0; x < 4; ++x) { a[x] = As[k][tm*4+x]; b[x] = Bs[k][tf*4+x]; }
#pragma unroll
      for (int x = 0; x < 4; ++x)
#pragma unroll
        for (int y = 0; y < 4; ++y) acc[x][y] += a[x]*b[y];
    }
    __syncthreads();
  }
#pragma unroll
  for (int x = 0; x < 4; ++x)
#pragma unroll
    for (int y = 0; y < 4; ++y)
      wgc[(size_t)l*FFD*HS + (size_t)(f0+tm*4+x)*HS + (j0+tf*4+y)] = f2bf(acc[x][y]);
}

__global__ __launch_bounds__(256) void transpose_scale_bf(
    const float* __restrict__ in, size_t inLS, int R, int C,
    const float* __restrict__ g, size_t gLS,
    unsigned short* __restrict__ out, size_t outLS) {
  __shared__ float tile[32][33];
  const int l = blockIdx.z, e0 = blockIdx.x*32, f0 = blockIdx.y*32;
  const int tx = threadIdx.x & 31, ty = threadIdx.x >> 5;
#pragma unroll
  for (int r = 0; r < 32; r += 8)
    tile[ty+r][tx] = in[(size_t)l*inLS + (size_t)(f0+ty+r)*C + e0 + tx];
  __syncthreads();
#pragma unroll
  for (int r = 0; r < 32; r += 8) {
    int e = e0 + ty + r, f = f0 + tx;
    float s = g ? g[(size_t)l*gLS + e] : 1.0f;
    out[(size_t)l*outLS + (size_t)e*R + f] = f2bf(tile[tx][ty+r] * s);
  }
}

__global__ __launch_bounds__(256) void bf16_copy(
    const float* __restrict__ in, unsigned short* __restrict__ out, size_t n) {
  for (size_t i = (size_t)blockIdx.x*256 + threadIdx.x; i < n; i += (size_t)gridDim.x*256)
    out[i] = f2bf(in[i]);
}

__global__ __launch_bounds__(256) void csa_kernel(
    const float* __restrict__ saWo, const float* __restrict__ sabin,
    const float* __restrict__ sabo, float* __restrict__ csa) {
  const int w = threadIdx.x >> 6, lane = threadIdx.x & 63;
  const int row = blockIdx.x*4 + w;
  const int l = row >> 9, f = row & 511;
  float acc = 0;
#pragma unroll
  for (int k = 0; k < 8; ++k) {
    int e = lane + 64*k;
    acc += saWo[((size_t)l*HS + f)*HS + e] * sabin[l*(3*HS) + 2*HS + e];
  }
  acc = wred(acc);
  if (lane == 0) csa[row] = acc + sabo[l*HS + f];
}

__global__ __launch_bounds__(256) void sqcbq_kernel(
    const float* __restrict__ caWin, const float* __restrict__ caBin,
    const float* __restrict__ lnG, const float* __restrict__ lnB,
    float* __restrict__ sq, float* __restrict__ cbq) {
  const int w = threadIdx.x >> 6, lane = threadIdx.x & 63;
  const int row = blockIdx.x*4 + w;
  const int l = row >> 9, f = row & 511;
  float a1 = 0, a2 = 0;
#pragma unroll
  for (int k = 0; k < 8; ++k) {
    int e = lane + 64*k;
    float wv = caWin[((size_t)l*(3*HS) + f)*HS + e];
    a1 += wv * lnG[l*(3*HS) + e];
    a2 += wv * lnB[l*(3*HS) + e];
  }
  a1 = wred(a1); a2 = wred(a2);
  if (lane == 0) { sq[row] = a1; cbq[row] = a2 + caBin[l*(3*HS) + f]; }
}

// su[l,k]=W1@g2; c1[l,k]=W1@(g2.bo); c2[l,k]=W1@b2 + ffB1
__global__ __launch_bounds__(256) void ffvec_kernel(
    const float* __restrict__ ffW1, const float* __restrict__ ffB1,
    const float* __restrict__ caBo,
    const float* __restrict__ lnG, const float* __restrict__ lnB,
    float* __restrict__ su, float* __restrict__ c1, float* __restrict__ c2) {
  const int w = threadIdx.x >> 6, lane = threadIdx.x & 63;
  const int row = blockIdx.x*4 + w;
  const int l = row >> 11, k = row & 2047;
  float a1 = 0, a2 = 0, a3 = 0;
#pragma unroll
  for (int q = 0; q < 8; ++q) {
    int e = lane + 64*q;
    float wv = ffW1[((size_t)l*FFD + k)*HS + e];
    float g2 = lnG[l*(3*HS) + HS + e];
    a1 += wv * g2;
    a2 += wv * g2 * caBo[l*HS + e];
    a3 += wv * lnB[l*(3*HS) + HS + e];
  }
  a1 = wred(a1); a2 = wred(a2); a3 = wred(a3);
  if (lane == 0) { su[row] = a1; c1[row] = a2; c2[row] = a3 + ffB1[(size_t)l*FFD + k]; }
}

// ---------------- main persistent sequential kernel ----------------
// Roles: Z 0-63 (update+z1) | T 64-95 (t1,t2) | A 96-223 (attn+z0/z2) | F 224-255 (ff)
// Per step: J1 -> J_T -> J2 -> s2-PW-join -> 1 grid barrier.

__global__ __launch_bounds__(NT, 2) void seq_kernel(
    const float* __restrict__ x,
    const float* __restrict__ Wx,  const float* __restrict__ bx,
    const float* __restrict__ Wh,  const float* __restrict__ bh,
    const float* __restrict__ caBo,
    const float* __restrict__ ffB2,
    const float* __restrict__ lnG,  const float* __restrict__ lnB,
    float* __restrict__ ws, float* __restrict__ out) {
  const unsigned short* Kb    = (const unsigned short*)(ws + OFF_KBF);
  const unsigned short* Vb    = (const unsigned short*)(ws + OFF_VBF);
  const unsigned short* Wcomb = (const unsigned short*)(ws + OFF_WCOMBBF);
  const unsigned short* WqT   = (const unsigned short*)(ws + OFF_WQTBF);
  const unsigned short* CaWob = (const unsigned short*)(ws + OFF_CAWOBF);
  const unsigned short* W2T   = (const unsigned short*)(ws + OFF_W2TBF);
  const unsigned short* F1b   = (const unsigned short*)(ws + OFF_FFW1BF);
  const unsigned short* WGCb  = (const unsigned short*)(ws + OFF_WGCBF);
  const float* csag  = ws + OFF_CSA;
  const float* sqg   = ws + OFF_SQ;
  const float* cbqg  = ws + OFF_CBQ;
  const float* suv   = ws + OFF_SU;
  const float* cf1   = ws + OFF_CF1;
  const float* cf2   = ws + OFF_CF2;
  float* hG    = ws + OFF_H;
  float* cG    = ws + OFF_C;
  float* xing  = ws + OFF_XING;
  float* z1g   = ws + OFF_Z1G;
  float* z02g  = ws + OFF_Z02G;
  float* t1g   = ws + OFF_T1G;
  float* t2g   = ws + OFF_T2G;
  float* YP    = ws + OFF_YP;
  float* CTXP  = ws + OFF_CTXP;
  float* Y2P   = ws + OFF_Y2P;
  float* denS  = ws + OFF_DENS;
  float* s1s   = ws + OFF_S1S;
  ull*   S2PW  = (ull*)(ws + OFF_S2PW);
  unsigned* J1     = (unsigned*)(ws + OFF_J1);
  unsigned* JT     = (unsigned*)(ws + OFF_JT);
  unsigned* J2     = (unsigned*)(ws + OFF_J2);
  unsigned* bflags = (unsigned*)(ws + OFF_FLAGS);

  __shared__ float sh_xin[HS], sh_h[HS], sh_vec[HS];
  __shared__ float sh_aux[64], sh_q[128], sh_p[64], sh_t1[16];
  __shared__ float sh_red[24], sh_den[4];

  const int bid = blockIdx.x, tid = threadIdx.x;
  const int w = tid >> 6, lane = tid & 63;
  const bool isZ = bid < 64;
  const bool isT = bid >= 64 && bid < 96;
  const bool isA = bid >= 96 && bid < 224;

  unsigned ph[64];     // packed bf16 prefetch (role-dependent usage)
  float pf32[16];      // f32 gate-weight rows (Z, A)

  auto pfrole = [&](int l) {
    if (isZ) {
      const float* wxr = Wx + (((size_t)l*3 + 1)*HS + bid*8 + w)*HS;
      const float* whr = Wh + (((size_t)l*3 + 1)*HS + bid*8 + w)*HS;
#pragma unroll
      for (int k = 0; k < 8; ++k) { pf32[k] = wxr[lane+64*k]; pf32[8+k] = whr[lane+64*k]; }
    } else if (isT) {
      const int b = bid - 64;
#pragma unroll
      for (int rr = 0; rr < 2; ++rr) {
        const unsigned short* base  = Wcomb + ((size_t)l*HS + b*16 + w*2 + rr)*HS;
        const unsigned short* cbase = CaWob + ((size_t)l*HS + b*16 + w*2 + rr)*HS;
#pragma unroll
        for (int kk = 0; kk < 4; ++kk) {
          ph[rr*4+kk]    = ldpack(base + lane + 128*kk,  base + lane + 64 + 128*kk);
          ph[16+rr*4+kk] = ldpack(cbase + lane + 128*kk, cbase + lane + 64 + 128*kk);
        }
      }
#pragma unroll
      for (int q = 0; q < 8; ++q)
        ph[8+q] = ldpack(WqT + ((size_t)l*HS + b*16 + 2*q)*HS + tid,
                         WqT + ((size_t)l*HS + b*16 + 2*q+1)*HS + tid);
    } else if (isA) {
      const int b2 = bid - 96, h = b2 >> 5, ms = b2 & 31;
      const int g4 = tid >> 7, dd = tid & 127;
#pragma unroll
      for (int rr = 0; rr < 8; ++rr) {
        const unsigned short* kr = Kb + ((size_t)l*MMEM + ms*64 + w*8 + rr)*HS + h*128;
        ph[rr] = ldpack(kr + lane, kr + lane + 64);
      }
#pragma unroll
      for (int q = 0; q < 8; ++q)
        ph[8+q] = ldpack(Vb + ((size_t)l*MMEM + ms*64 + g4*16 + 2*q)*HS + h*128 + dd,
                         Vb + ((size_t)l*MMEM + ms*64 + g4*16 + 2*q+1)*HS + h*128 + dd);
      const int rowid = b2*8 + w, g = (rowid < 512) ? 0 : 2, f = rowid & 511;
      const float* wxr = Wx + (((size_t)l*3 + g)*HS + f)*HS;
      const float* whr = Wh + (((size_t)l*3 + g)*HS + f)*HS;
#pragma unroll
      for (int k = 0; k < 8; ++k) { pf32[k] = wxr[lane+64*k]; pf32[8+k] = whr[lane+64*k]; }
    } else {
      const int fb = bid - 224;
#pragma unroll
      for (int q = 0; q < 8; ++q) {
        const unsigned short* b1 = F1b  + ((size_t)l*FFD + fb*64 + w*8 + q)*HS;
        const unsigned short* b2 = WGCb + ((size_t)l*FFD + fb*64 + w*8 + q)*HS;
#pragma unroll
        for (int kk = 0; kk < 4; ++kk) {
          ph[q*4+kk]    = ldpack(b1 + lane + 128*kk, b1 + lane + 64 + 128*kk);
          ph[32+q*4+kk] = ldpack(b2 + lane + 128*kk, b2 + lane + 64 + 128*kk);
        }
      }
    }
  };

  // fused LSTM update for step s-1 (Z blocks; inputs covered by the step barrier)
  auto do_update = [&](int ip, int parp, float& xn, float& cn) {
    const int j = tid;
    float t2v = ald(t2g + j);
    float z0  = ald(z02g + j);
    float z2  = ald(z02g + HS + j);
    float y2 = 0;
    {
      float yv[16];
#pragma unroll
      for (int c = 0; c < 32; c += 16) {
#pragma unroll
        for (int p = 0; p < 16; ++p) yv[p] = ald(Y2P + (size_t)(c+p)*HS + j);
#pragma unroll
        for (int p = 0; p < 16; ++p) y2 += yv[p];
      }
    }
    if (w == 0) {
      float a = (lane < 32) ? pwval(S2PW + lane*2) : pwval(S2PW + (lane-32)*2 + 1);
#pragma unroll
      for (int m = 16; m; m >>= 1) a += __shfl_xor(a, m);
      if (lane == 0)  sh_red[16] = a;
      if (lane == 32) sh_red[17] = a;
    }
    __syncthreads();
    float m2 = sh_red[16]*INV512;
    float r2 = rsqrtf(sh_red[17]*INV512 - m2*m2 + 1e-5f);
    float x2 = (t2v-m2)*r2*lnG[(ip*3+1)*HS+j] + lnB[(ip*3+1)*HS+j];
    float t3 = x2 + y2 + ffB2[ip*HS + j];
    float s_ = t3, q_ = t3*t3;
#pragma unroll
    for (int m = 32; m; m >>= 1) { s_ += __shfl_xor(s_, m); q_ += __shfl_xor(q_, m); }
    if (lane == 0) { sh_red[w] = s_; sh_red[8+w] = q_; }
    __syncthreads();
    if (tid == 0) {
      float a = 0, b = 0;
#pragma unroll
      for (int k = 0; k < 8; ++k) { a += sh_red[k]; b += sh_red[8+k]; }
      sh_red[0] = a; sh_red[1] = b;
    }
    __syncthreads();
    float m3 = sh_red[0]*INV512;
    float r3 = rsqrtf(sh_red[1]*INV512 - m3*m3 + 1e-5f);
    float d  = (t3-m3)*r3*lnG[(ip*3+2)*HS+j] + lnB[(ip*3+2)*HS+j];
    float cp = ald(cG + (parp*LNUM + ip)*HS + j);
    float ft = sigm(cp - d);
    float it = sigm(z0);
    float gt = tanhf(z2);
    cn = ft*cp + it*gt;
    xn = tanhf(cn);
  };

  pfrole(0);

  for (int s = 0; s < TT*LNUM; ++s) {
    const int t = s >> 2, i = s & 3;
    const int par = t & 1;
    const unsigned jv = (unsigned)(s + 1);

    if (isZ) {
      // ---- W1: update(s-1) + z1 matvec ----
      float xn = 0.f, cn = 0.f;
      if (s > 0 && (bid == 0 || i > 0)) {
        const int ip = (s-1) & 3, tp = (s-1) >> 2, parp = tp & 1;
        do_update(ip, parp, xn, cn);
        if (bid == 0) {
          ast(hG + ((parp^1)*LNUM + ip)*HS + tid, xn);
          ast(cG + ((parp^1)*LNUM + ip)*HS + tid, cn);
          if (ip == 3) out[tp*HS + tid] = xn;
        }
      }
      float xv = (i == 0) ? x[t*HS + tid] : xn;
      sh_xin[tid] = xv;
      sh_h[tid]   = ald(hG + (par*LNUM + i)*HS + tid);
      if (bid == 0) ast(xing + tid, xv);
      __syncthreads();
      const int f = bid*8 + w;
      float acc = 0;
#pragma unroll
      for (int k = 0; k < 8; ++k) {
        int e = lane + 64*k;
        acc += pf32[k]*sh_xin[e] + pf32[8+k]*sh_h[e];
      }
      acc = wred(acc);
      if (lane == 0) ast(z1g + f, acc + bx[(i*3+1)*HS + f] + bh[(i*3+1)*HS + f]);
      jflag(J1, bid, jv);
    } else if (isT) {
      const int b = bid - 64;
      // ---- t1 window ----
      jwait(J1, 64, jv);
      sh_vec[tid] = sigm(ald(z1g + tid));  // f0
      __syncthreads();
#pragma unroll
      for (int rr = 0; rr < 2; ++rr) {
        const int r = w*2 + rr, j = b*16 + r;
        float acc = 0;
#pragma unroll
        for (int kk = 0; kk < 4; ++kk) {
          unsigned pw = ph[rr*4+kk];
          acc += bflo(pw)*sh_vec[lane+128*kk] + bfhi(pw)*sh_vec[lane+64+128*kk];
        }
        acc = wred(acc);
        if (lane == 0) {
          float t1v = sh_vec[j] + acc + csag[i*HS + j];
          sh_t1[r] = t1v;
          ast(t1g + j, t1v);
        }
      }
      __syncthreads();
      {   // Y owner plane
        float yl = 0;
#pragma unroll
        for (int q = 0; q < 8; ++q) {
          unsigned pw = ph[8+q];
          yl += sh_t1[2*q]*bflo(pw) + sh_t1[2*q+1]*bfhi(pw);
        }
        ast(YP + (size_t)b*HS + tid, yl);
      }
      if (w == 0 && lane < 16) {
        float v = sh_t1[lane], s_ = v, q_ = v*v;
#pragma unroll
        for (int m = 8; m; m >>= 1) { s_ += __shfl_xor(s_, m); q_ += __shfl_xor(q_, m); }
        if (lane == 0) { ast(s1s + b*2, s_); ast(s1s + b*2 + 1, q_); }
      }
      jflag(JT, b, jv);
      // ---- t2 window ----
      jwait(J2, 128, jv);
      {   // ctx sum (32 planes, pipelined)
        const int hh = tid >> 7, dd = tid & 127;
        float ctxa = 0;
        {
          float cv[16];
#pragma unroll
          for (int c = 0; c < 32; c += 16) {
#pragma unroll
            for (int p = 0; p < 16; ++p)
              cv[p] = ald(CTXP + (size_t)(hh*32 + c + p)*128 + dd);
#pragma unroll
            for (int p = 0; p < 16; ++p) ctxa += cv[p];
          }
        }
        slotred32(s1s, sh_red, 18, w, lane);
        if (w >= 4) {
          float v = (lane < 32) ? ald(denS + (w-4)*32 + lane) : 0.f;
#pragma unroll
          for (int m = 16; m; m >>= 1) v += __shfl_xor(v, m);
          if (lane == 0) sh_den[w-4] = v;
        }
        __syncthreads();
        sh_vec[tid] = ctxa / sh_den[hh];
      }
      __syncthreads();
      const float m1 = sh_red[18]*INV512;
      const float r1 = rsqrtf(sh_red[19]*INV512 - m1*m1 + 1e-5f);
#pragma unroll
      for (int rr = 0; rr < 2; ++rr) {
        const int r = w*2 + rr, j = b*16 + r;
        float a2 = 0;
#pragma unroll
        for (int kk = 0; kk < 4; ++kk) {
          unsigned pw = ph[16+rr*4+kk];
          a2 += bflo(pw)*sh_vec[lane+128*kk] + bfhi(pw)*sh_vec[lane+64+128*kk];
        }
        a2 = wred(a2);
        if (lane == 0) {
          float x1 = (sh_t1[r]-m1)*r1*lnG[(i*3)*HS + j] + lnB[(i*3)*HS + j];
          float t2v = x1 + a2 + caBo[i*HS + j];
          ast(t2g + j, t2v);
          sh_aux[r] = t2v;
        }
      }
      __syncthreads();
      if (w == 0 && lane < 16) {
        float v = sh_aux[lane], s_ = v, q_ = v*v;
#pragma unroll
        for (int m = 8; m; m >>= 1) { s_ += __shfl_xor(s_, m); q_ += __shfl_xor(q_, m); }
        if (lane == 0) { pwst(S2PW + b*2, jv, s_); pwst(S2PW + b*2 + 1, jv, q_); }
      }
    } else if (isA) {
      const int b2 = bid - 96, h = b2 >> 5;
      const int g4 = tid >> 7, dd = tid & 127;
      jwait(JT, 32, jv);
      {   // Y sum: 8 planes per thread-group
        float part = 0;
        float yv[8];
#pragma unroll
        for (int p = 0; p < 8; ++p) yv[p] = ald(YP + (size_t)(g4*8+p)*HS + h*128 + dd);
#pragma unroll
        for (int p = 0; p < 8; ++p) part += yv[p];
        sh_vec[tid] = part;
      }
      slotred32(s1s, sh_red, 18, w, lane);
      __syncthreads();
      if (tid < 128) {
        float Ysum = sh_vec[tid] + sh_vec[128+tid] + sh_vec[256+tid] + sh_vec[384+tid];
        float m1 = sh_red[18]*INV512;
        float r1 = rsqrtf(sh_red[19]*INV512 - m1*m1 + 1e-5f);
        int f = h*128 + tid;
        sh_q[tid] = r1*(Ysum - m1*sqg[i*HS + f]) + cbqg[i*HS + f];
      }
      __syncthreads();
#pragma unroll
      for (int rr = 0; rr < 8; ++rr) {
        unsigned pw = ph[rr];
        float sc = sh_q[lane]*bflo(pw) + sh_q[lane+64]*bfhi(pw);
        sc = wred(sc);
        if (lane == 0) sh_p[w*8+rr] = __expf(sc * QSCALE);
      }
      __syncthreads();
      {   // ctx partial
        float acc = 0;
#pragma unroll
        for (int q = 0; q < 8; ++q) {
          unsigned pw = ph[8+q];
          acc += sh_p[g4*16 + 2*q]*bflo(pw) + sh_p[g4*16 + 2*q+1]*bfhi(pw);
        }
        sh_vec[tid] = acc;
      }
      if (w == 0) {
        float v = wred(sh_p[lane]);
        if (lane == 0) ast(denS + b2, v);
      }
      __syncthreads();
      if (tid < 128) {
        float tot = sh_vec[tid] + sh_vec[128+tid] + sh_vec[256+tid] + sh_vec[384+tid];
        ast(CTXP + (size_t)b2*128 + tid, tot);
      }
      jflag(J2, b2, jv);
      // ---- z0/z2 matvec (consumed next step's W1) ----
      sh_xin[tid] = ald(xing + tid);
      sh_h[tid]   = ald(hG + (par*LNUM + i)*HS + tid);
      __syncthreads();
      {
        const int rowid = b2*8 + w, g = (rowid < 512) ? 0 : 2, f = rowid & 511;
        float acc = 0;
#pragma unroll
        for (int k = 0; k < 8; ++k) {
          int e = lane + 64*k;
          acc += pf32[k]*sh_xin[e] + pf32[8+k]*sh_h[e];
        }
        acc = wred(acc);
        if (lane == 0)
          ast(z02g + (g ? HS : 0) + f, acc + bx[(i*3+g)*HS + f] + bh[(i*3+g)*HS + f]);
      }
    } else {
      const int fb = bid - 224;
      jwait(JT, 32, jv);
      float t1v = ald(t1g + tid);
      slotred32(s1s, sh_red, 18, w, lane);
      __syncthreads();
      {
        const float m1 = sh_red[18]*INV512;
        const float r1 = rsqrtf(sh_red[19]*INV512 - m1*m1 + 1e-5f);
        sh_xin[tid] = ((t1v - m1)*r1*lnG[(i*3)*HS + tid] + lnB[(i*3)*HS + tid])
                      * lnG[(i*3+1)*HS + tid];      // x1g = x1 * g2
      }
      jwait(J2, 128, jv);
      {   // ctxn
        const int hh = tid >> 7, dd = tid & 127;
        float ctxa = 0;
        {
          float cv[16];
#pragma unroll
          for (int c = 0; c < 32; c += 16) {
#pragma unroll
            for (int p = 0; p < 16; ++p)
              cv[p] = ald(CTXP + (size_t)(hh*32 + c + p)*128 + dd);
#pragma unroll
            for (int p = 0; p < 16; ++p) ctxa += cv[p];
          }
        }
        if (w >= 4) {
          float v = (lane < 32) ? ald(denS + (w-4)*32 + lane) : 0.f;
#pragma unroll
          for (int m = 16; m; m >>= 1) v += __shfl_xor(v, m);
          if (lane == 0) sh_den[w-4] = v;
        }
        __syncthreads();
        sh_vec[tid] = ctxa / sh_den[hh];
      }
      __syncthreads();
      float u[8];
#pragma unroll
      for (int q = 0; q < 8; ++q) {
        float acc = 0;
#pragma unroll
        for (int kk = 0; kk < 4; ++kk) {
          unsigned pw1 = ph[q*4+kk], pw2 = ph[32+q*4+kk];
          acc += bflo(pw1)*sh_xin[lane+128*kk] + bfhi(pw1)*sh_xin[lane+64+128*kk]
               + bflo(pw2)*sh_vec[lane+128*kk] + bfhi(pw2)*sh_vec[lane+64+128*kk];
        }
        u[q] = wred(acc);
      }
      // s2 late join
      if (w == 0) {
        float a = (lane < 32) ? pwpoll(S2PW + lane*2, jv) : pwpoll(S2PW + (lane-32)*2 + 1, jv);
#pragma unroll
        for (int m = 16; m; m >>= 1) a += __shfl_xor(a, m);
        if (lane == 0)  sh_red[16] = a;
        if (lane == 32) sh_red[17] = a;
      }
      __syncthreads();
      const float m2 = sh_red[16]*INV512;
      const float r2 = rsqrtf(sh_red[17]*INV512 - m2*m2 + 1e-5f);
      if (lane == 0) {
#pragma unroll
        for (int q = 0; q < 8; ++q) {
          int row = fb*64 + w*8 + q;
          sh_aux[w*8+q] = fmaxf(r2*(u[q] + cf1[i*FFD + row] - m2*suv[i*FFD + row])
                                + cf2[i*FFD + row], 0.f);
        }
      }
      __syncthreads();
      {   // Y2 owner plane; W2T read at use (L2-resident, packed)
        float yl = 0;
#pragma unroll
        for (int q = 0; q < 32; ++q) {
          unsigned pw = ldpack(W2T + ((size_t)i*FFD + fb*64 + 2*q)*HS + tid,
                               W2T + ((size_t)i*FFD + fb*64 + 2*q+1)*HS + tid);
          yl += sh_aux[2*q]*bflo(pw) + sh_aux[2*q+1]*bfhi(pw);
        }
        ast(Y2P + (size_t)fb*HS + tid, yl);
      }
    }
    gridbar(bflags, jv, [&]{ pfrole((s+1) & 3); });
  }

  // ---------- epilogue: final update (t=127, i=3) + output assembly ----------
  if (bid == 0) {
    float xn, cn;
    do_update(3, 1, xn, cn);
    out[127*HS + tid] = xn;
    out[TT*HS + 3*HS + tid] = xn;                 // h_T[3]
    out[TT*HS + LNUM*HS + 3*HS + tid] = cn;       // c_T[3]
#pragma unroll
    for (int ii = 0; ii < 3; ++ii) {
      out[TT*HS + ii*HS + tid]            = ald(hG + (0*LNUM + ii)*HS + tid);
      out[TT*HS + LNUM*HS + ii*HS + tid]  = ald(cG + (0*LNUM + ii)*HS + tid);
    }
  }
}

// ---------------- host launcher ----------------
extern "C" void kernel_launch(void* const* d_in, const int* in_sizes, int n_in,
                              void* d_out, int out_size, void* d_ws, size_t ws_size,
                              hipStream_t stream) {
  const float* x      = (const float*)d_in[0];
  const float* hist   = (const float*)d_in[1];
  const float* Wx     = (const float*)d_in[2];
  const float* bx     = (const float*)d_in[3];
  const float* Wh     = (const float*)d_in[4];
  const float* bh     = (const float*)d_in[5];
  const float* saWin  = (const float*)d_in[6];
  const float* saBin  = (const float*)d_in[7];
  const float* saWo   = (const float*)d_in[8];
  const float* saBo   = (const float*)d_in[9];
  const float* caWin  = (const float*)d_in[10];
  const float* caBin  = (const float*)d_in[11];
  const float* caWo   = (const float*)d_in[12];
  const float* caBo   = (const float*)d_in[13];
  const float* ffW1   = (const float*)d_in[14];
  const float* ffB1   = (const float*)d_in[15];
  const float* ffW2   = (const float*)d_in[16];
  const float* ffB2   = (const float*)d_in[17];
  const float* lnG    = (const float*)d_in[18];
  const float* lnB    = (const float*)d_in[19];
  float* ws  = (float*)d_ws;
  float* out = (float*)d_out;

  hipMemsetAsync((char*)d_ws + OFF_STATE*sizeof(float), 0,
                 (WS_TOTAL - OFF_STATE)*sizeof(float), stream);

  kv_gemm<<<dim3(MMEM/64, HS/64, LNUM), 256, 0, stream>>>(
      hist, caWin, caBin, (unsigned short*)(ws + OFF_KBF), HS);
  kv_gemm<<<dim3(MMEM/64, HS/64, LNUM), 256, 0, stream>>>(
      hist, caWin, caBin, (unsigned short*)(ws + OFF_VBF), 2*HS);
  wcomb_gemm<<<dim3(HS/64, HS/64, LNUM), 256, 0, stream>>>(
      saWo, saWin, (unsigned short*)(ws + OFF_WCOMBBF));
  wgc_gemm<<<dim3(FFD/64, HS/64, LNUM), 256, 0, stream>>>(
      ffW1, lnG, caWo, (unsigned short*)(ws + OFF_WGCBF));
  csa_kernel<<<(LNUM*HS)/4, 256, 0, stream>>>(saWo, saBin, saBo, ws + OFF_CSA);
  transpose_scale_bf<<<dim3(HS/32, HS/32, LNUM), 256, 0, stream>>>(
      caWin, (size_t)(3*HS)*HS, HS, HS, lnG, (size_t)(3*HS),
      (unsigned short*)(ws + OFF_WQTBF), (size_t)HS*HS);
  sqcbq_kernel<<<(LNUM*HS)/4, 256, 0, stream>>>(caWin, caBin, lnG, lnB, ws + OFF_SQ, ws + OFF_CBQ);
  transpose_scale_bf<<<dim3(FFD/32, HS/32, LNUM), 256, 0, stream>>>(
      ffW2, (size_t)HS*FFD, HS, FFD, nullptr, 0,
      (unsigned short*)(ws + OFF_W2TBF), (size_t)FFD*HS);
  bf16_copy<<<2048, 256, 0, stream>>>(ffW1, (unsigned short*)(ws + OFF_FFW1BF),
                                      (size_t)LNUM*FFD*HS);
  bf16_copy<<<1024, 256, 0, stream>>>(caWo, (unsigned short*)(ws + OFF_CAWOBF),
                                      (size_t)LNUM*HS*HS);
  ffvec_kernel<<<(LNUM*FFD)/4, 256, 0, stream>>>(ffW1, ffB1, caBo, lnG, lnB,
      ws + OFF_SU, ws + OFF_CF1, ws + OFF_CF2);

  seq_kernel<<<NB, NT, 0, stream>>>(x, Wx, bx, Wh, bh, caBo,
                                    ffB2, lnG, lnB, ws, out);
}

// Round 9
// 19562.932 us; speedup vs baseline: 1.2675x; 1.2242x over previous
//
#include <hip/hip_runtime.h>

#define HS   512
#define LNUM 4
#define TT   128
#define MMEM 2048
#define FFD  2048
#define NB   256
#define NT   512
#define INV512 (1.0f/512.0f)
#define QSCALE 0.08838834764831845f  // 1/sqrt(128)
#define NWIN  659                    // 5*128 + 6*3 + 1

typedef unsigned short ushortt;

// ---------------- workspace layout (float offsets) ----------------
constexpr size_t KHALF  = (size_t)LNUM*MMEM*HS/2;
constexpr size_t HHALF  = (size_t)LNUM*HS*HS/2;
constexpr size_t FHALF  = (size_t)LNUM*FFD*HS/2;
constexpr size_t GHALF  = (size_t)LNUM*3*HS*HS/2;
constexpr size_t OFF_KBF    = 0;
constexpr size_t OFF_VBF    = OFF_KBF    + KHALF;
constexpr size_t OFF_WCOMBBF= OFF_VBF    + KHALF;
constexpr size_t OFF_WQTBF  = OFF_WCOMBBF+ HHALF;
constexpr size_t OFF_CAWOBF = OFF_WQTBF  + HHALF;
constexpr size_t OFF_W2TBF  = OFF_CAWOBF + HHALF;
constexpr size_t OFF_FFW1BF = OFF_W2TBF  + FHALF;
constexpr size_t OFF_WGCBF  = OFF_FFW1BF + FHALF;
constexpr size_t OFF_WXBF   = OFF_WGCBF  + FHALF;
constexpr size_t OFF_WHBF   = OFF_WXBF   + GHALF;
constexpr size_t OFF_CSA    = OFF_WHBF   + GHALF;                // L*HS
constexpr size_t OFF_SQ     = OFF_CSA    + (size_t)LNUM*HS;
constexpr size_t OFF_CBQ    = OFF_SQ     + (size_t)LNUM*HS;
constexpr size_t OFF_SU     = OFF_CBQ    + (size_t)LNUM*HS;      // L*FF
constexpr size_t OFF_CF1    = OFF_SU     + (size_t)LNUM*FFD;
constexpr size_t OFF_CF2    = OFF_CF1    + (size_t)LNUM*FFD;
// mutable (memset 0)
constexpr size_t OFF_STATE  = OFF_CF2    + (size_t)LNUM*FFD;
constexpr size_t OFF_HX     = OFF_STATE;                         // [4][512]
constexpr size_t OFF_Z1     = OFF_HX     + 4*HS;                 // [4][512]
constexpr size_t OFF_Z02    = OFF_Z1     + 4*HS;                 // [4][2][1024]
constexpr size_t OFF_T1     = OFF_Z02    + 4*2*2*HS;             // [4][512]
constexpr size_t OFF_T2     = OFF_T1     + 4*HS;                 // [4][512]
constexpr size_t OFF_YP     = OFF_T2     + 4*HS;                 // [4][32][512]
constexpr size_t OFF_CTXP   = OFF_YP     + 4*32*HS;              // [4][32][128]
constexpr size_t OFF_Y2P    = OFF_CTXP   + 4*32*128;             // [4][32][512]
constexpr size_t OFF_DENS   = OFF_Y2P    + 4*32*HS;              // [4][32]
constexpr size_t OFF_S1S    = OFF_DENS   + 4*32;                 // [4][64]
constexpr size_t OFF_S2S    = OFF_S1S    + 4*64;                 // [4][64]
constexpr size_t OFF_FLAGS  = OFF_S2S    + 4*64;                 // NB*32 u32
constexpr size_t WS_TOTAL   = OFF_FLAGS  + (size_t)NB*32;

__device__ __forceinline__ float wred(float v) {
#pragma unroll
  for (int m = 32; m; m >>= 1) v += __shfl_xor(v, m);
  return v;
}
__device__ __forceinline__ float sigm(float x) { return 1.0f/(1.0f+__expf(-x)); }
__device__ __forceinline__ ushortt f2bf(float f) {
  unsigned u = __float_as_uint(f);
  return (ushortt)((u + 0x7fffu + ((u >> 16) & 1u)) >> 16);
}
__device__ __forceinline__ float bflo(unsigned v){ return __uint_as_float(v << 16); }
__device__ __forceinline__ float bfhi(unsigned v){ return __uint_as_float(v & 0xffff0000u); }
__device__ __forceinline__ unsigned ldpack(const ushortt* a, const ushortt* b){
  return (unsigned)(*a) | ((unsigned)(*b) << 16);
}
__device__ __forceinline__ float ald(const float* p) {
  return __hip_atomic_load(p, __ATOMIC_RELAXED, __HIP_MEMORY_SCOPE_AGENT);
}
__device__ __forceinline__ void ast(float* p, float v) {
  __hip_atomic_store(p, v, __ATOMIC_RELAXED, __HIP_MEMORY_SCOPE_AGENT);
}
__device__ __forceinline__ unsigned aldu(const unsigned* p) {
  return __hip_atomic_load(p, __ATOMIC_RELAXED, __HIP_MEMORY_SCOPE_AGENT);
}
__device__ __forceinline__ void astu(unsigned* p, unsigned v) {
  __hip_atomic_store(p, v, __ATOMIC_RELAXED, __HIP_MEMORY_SCOPE_AGENT);
}

// direct-poll grid barrier (R6-proven)
__device__ __forceinline__ void gridbar(unsigned* flags, unsigned g) {
  asm volatile("s_waitcnt vmcnt(0)" ::: "memory");
  __syncthreads();
  if (threadIdx.x == 0) astu(flags + (size_t)blockIdx.x*32, g);
  if (threadIdx.x < NB) {
    const unsigned* f = flags + (size_t)threadIdx.x*32;
    while ((int)(aldu(f) - g) < 0) __builtin_amdgcn_s_sleep(2);
  }
  __syncthreads();
}

// warp0: reduce 32 (sum,sumsq) slot pairs -> sh[o], sh[o+1]
__device__ __forceinline__ void slotred32(const float* slots, float* sh, int o,
                                          int w, int lane) {
  if (w == 0) {
    float a = (lane < 32) ? ald(slots + lane*2) : ald(slots + (lane-32)*2 + 1);
#pragma unroll
    for (int m = 16; m; m >>= 1) a += __shfl_xor(a, m);
    if (lane == 0)  sh[o]   = a;
    if (lane == 32) sh[o+1] = a;
  }
}

// ---------------- precompute kernels (R6/R8-proven) ----------------

__global__ __launch_bounds__(256) void kv_gemm(
    const float* __restrict__ hist, const float* __restrict__ caWin,
    const float* __restrict__ caBin, ushortt* __restrict__ out, int koff) {
  __shared__ float As[16][64];
  __shared__ float Bs[16][64];
  const int l = blockIdx.z, m0 = blockIdx.x*64, f0 = blockIdx.y*64;
  const int tid = threadIdx.x, tm = tid >> 4, tf = tid & 15;
  float acc[4][4] = {};
  for (int e0 = 0; e0 < HS; e0 += 16) {
#pragma unroll
    for (int it = 0; it < 4; ++it) {
      int idx = tid + it*256, k = idx & 15, mm = idx >> 4;
      As[k][mm] = hist[((size_t)(m0+mm)*LNUM + l)*HS + e0 + k];
      Bs[k][mm] = caWin[((size_t)l*(3*HS) + koff + f0 + mm)*HS + e0 + k];
    }
    __syncthreads();
#pragma unroll
    for (int k = 0; k < 16; ++k) {
      float a[4], b[4];
#pragma unroll
      for (int xx = 0; xx < 4; ++xx) { a[xx] = As[k][tm*4+xx]; b[xx] = Bs[k][tf*4+xx]; }
#pragma unroll
      for (int xx = 0; xx < 4; ++xx)
#pragma unroll
        for (int y = 0; y < 4; ++y) acc[xx][y] += a[xx]*b[y];
    }
    __syncthreads();
  }
#pragma unroll
  for (int xx = 0; xx < 4; ++xx)
#pragma unroll
    for (int y = 0; y < 4; ++y) {
      int m = m0 + tm*4 + xx, f = f0 + tf*4 + y;
      out[((size_t)l*MMEM + m)*HS + f] = f2bf(acc[xx][y] + caBin[l*(3*HS) + koff + f]);
    }
}

__global__ __launch_bounds__(256) void wcomb_gemm(
    const float* __restrict__ saWo, const float* __restrict__ saWin,
    ushortt* __restrict__ wcomb) {
  __shared__ float As[16][64];
  __shared__ float Bs[16][64];
  const int l = blockIdx.z, f0 = blockIdx.x*64, j0 = blockIdx.y*64;
  const int tid = threadIdx.x, tm = tid >> 4, tf = tid & 15;
  float acc[4][4] = {};
  for (int e0 = 0; e0 < HS; e0 += 16) {
#pragma unroll
    for (int it = 0; it < 4; ++it) {
      int idx = tid + it*256;
      { int k = idx & 15, ff = idx >> 4;
        As[k][ff] = saWo[((size_t)l*HS + f0+ff)*HS + e0 + k]; }
      { int jj = idx & 63, k = idx >> 6;
        Bs[k][jj] = saWin[((size_t)l*(3*HS) + 2*HS + e0 + k)*HS + j0 + jj]; }
    }
    __syncthreads();
#pragma unroll
    for (int k = 0; k < 16; ++k) {
      float a[4], b[4];
#pragma unroll
      for (int xx = 0; xx < 4; ++xx) { a[xx] = As[k][tm*4+xx]; b[xx] = Bs[k][tf*4+xx]; }
#pragma unroll
      for (int xx = 0; xx < 4; ++xx)
#pragma unroll
        for (int y = 0; y < 4; ++y) acc[xx][y] += a[xx]*b[y];
    }
    __syncthreads();
  }
#pragma unroll
  for (int xx = 0; xx < 4; ++xx)
#pragma unroll
    for (int y = 0; y < 4; ++y)
      wcomb[(size_t)l*HS*HS + (size_t)(f0+tm*4+xx)*HS + (j0+tf*4+y)] = f2bf(acc[xx][y]);
}

__global__ __launch_bounds__(256) void wgc_gemm(
    const float* __restrict__ ffW1, const float* __restrict__ lnG,
    const float* __restrict__ caWo, ushortt* __restrict__ wgc) {
  __shared__ float As[16][64];
  __shared__ float Bs[16][64];
  const int l = blockIdx.z, f0 = blockIdx.x*64, j0 = blockIdx.y*64;
  const int tid = threadIdx.x, tm = tid >> 4, tf = tid & 15;
  float acc[4][4] = {};
  for (int e0 = 0; e0 < HS; e0 += 16) {
#pragma unroll
    for (int it = 0; it < 4; ++it) {
      int idx = tid + it*256;
      { int k = idx & 15, ff = idx >> 4;
        As[k][ff] = ffW1[((size_t)l*FFD + f0+ff)*HS + e0 + k] * lnG[l*(3*HS) + HS + e0 + k]; }
      { int jj = idx & 63, k = idx >> 6;
        Bs[k][jj] = caWo[((size_t)l*HS + e0 + k)*HS + j0 + jj]; }
    }
    __syncthreads();
#pragma unroll
    for (int k = 0; k < 16; ++k) {
      float a[4], b[4];
#pragma unroll
      for (int xx = 0; xx < 4; ++xx) { a[xx] = As[k][tm*4+xx]; b[xx] = Bs[k][tf*4+xx]; }
#pragma unroll
      for (int xx = 0; xx < 4; ++xx)
#pragma unroll
        for (int y = 0; y < 4; ++y) acc[xx][y] += a[xx]*b[y];
    }
    __syncthreads();
  }
#pragma unroll
  for (int xx = 0; xx < 4; ++xx)
#pragma unroll
    for (int y = 0; y < 4; ++y)
      wgc[(size_t)l*FFD*HS + (size_t)(f0+tm*4+xx)*HS + (j0+tf*4+y)] = f2bf(acc[xx][y]);
}

__global__ __launch_bounds__(256) void transpose_scale_bf(
    const float* __restrict__ in, size_t inLS, int R, int C,
    const float* __restrict__ g, size_t gLS,
    ushortt* __restrict__ out, size_t outLS) {
  __shared__ float tile[32][33];
  const int l = blockIdx.z, e0 = blockIdx.x*32, f0 = blockIdx.y*32;
  const int tx = threadIdx.x & 31, ty = threadIdx.x >> 5;
#pragma unroll
  for (int r = 0; r < 32; r += 8)
    tile[ty+r][tx] = in[(size_t)l*inLS + (size_t)(f0+ty+r)*C + e0 + tx];
  __syncthreads();
#pragma unroll
  for (int r = 0; r < 32; r += 8) {
    int e = e0 + ty + r, f = f0 + tx;
    float s = g ? g[(size_t)l*gLS + e] : 1.0f;
    out[(size_t)l*outLS + (size_t)e*R + f] = f2bf(tile[tx][ty+r] * s);
  }
}

__global__ __launch_bounds__(256) void bf16_copy(
    const float* __restrict__ in, ushortt* __restrict__ out, size_t n) {
  for (size_t i = (size_t)blockIdx.x*256 + threadIdx.x; i < n; i += (size_t)gridDim.x*256)
    out[i] = f2bf(in[i]);
}

__global__ __launch_bounds__(256) void csa_kernel(
    const float* __restrict__ saWo, const float* __restrict__ sabin,
    const float* __restrict__ sabo, float* __restrict__ csa) {
  const int w = threadIdx.x >> 6, lane = threadIdx.x & 63;
  const int row = blockIdx.x*4 + w;
  const int l = row >> 9, f = row & 511;
  float acc = 0;
#pragma unroll
  for (int k = 0; k < 8; ++k) {
    int e = lane + 64*k;
    acc += saWo[((size_t)l*HS + f)*HS + e] * sabin[l*(3*HS) + 2*HS + e];
  }
  acc = wred(acc);
  if (lane == 0) csa[row] = acc + sabo[l*HS + f];
}

__global__ __launch_bounds__(256) void sqcbq_kernel(
    const float* __restrict__ caWin, const float* __restrict__ caBin,
    const float* __restrict__ lnG, const float* __restrict__ lnB,
    float* __restrict__ sq, float* __restrict__ cbq) {
  const int w = threadIdx.x >> 6, lane = threadIdx.x & 63;
  const int row = blockIdx.x*4 + w;
  const int l = row >> 9, f = row & 511;
  float a1 = 0, a2 = 0;
#pragma unroll
  for (int k = 0; k < 8; ++k) {
    int e = lane + 64*k;
    float wv = caWin[((size_t)l*(3*HS) + f)*HS + e];
    a1 += wv * lnG[l*(3*HS) + e];
    a2 += wv * lnB[l*(3*HS) + e];
  }
  a1 = wred(a1); a2 = wred(a2);
  if (lane == 0) { sq[row] = a1; cbq[row] = a2 + caBin[l*(3*HS) + f]; }
}

__global__ __launch_bounds__(256) void ffvec_kernel(
    const float* __restrict__ ffW1, const float* __restrict__ ffB1,
    const float* __restrict__ caBo,
    const float* __restrict__ lnG, const float* __restrict__ lnB,
    float* __restrict__ su, float* __restrict__ c1, float* __restrict__ c2) {
  const int w = threadIdx.x >> 6, lane = threadIdx.x & 63;
  const int row = blockIdx.x*4 + w;
  const int l = row >> 11, k = row & 2047;
  float a1 = 0, a2 = 0, a3 = 0;
#pragma unroll
  for (int q = 0; q < 8; ++q) {
    int e = lane + 64*q;
    float wv = ffW1[((size_t)l*FFD + k)*HS + e];
    float g2 = lnG[l*(3*HS) + HS + e];
    a1 += wv * g2;
    a2 += wv * g2 * caBo[l*HS + e];
    a3 += wv * lnB[l*(3*HS) + HS + e];
  }
  a1 = wred(a1); a2 = wred(a2); a3 = wred(a3);
  if (lane == 0) { su[row] = a1; c1[row] = a2; c2[row] = a3 + ffB1[(size_t)l*FFD + k]; }
}

// ---------------- main wavefront-pipelined persistent kernel ----------------
// 4 groups x 64 blocks; group g owns layer g. Cell (t,i) at windows 5t+6i+{0..4}.
// A = blocks 0-31 of group (t1/attn/t2); B = 32-63 (update/z-gates/ff).

__global__ __launch_bounds__(NT, 2) void seq_kernel(
    const float* __restrict__ x,
    const float* __restrict__ bx, const float* __restrict__ bh,
    const float* __restrict__ caBo, const float* __restrict__ ffB2,
    const float* __restrict__ lnG,  const float* __restrict__ lnB,
    float* __restrict__ ws, float* __restrict__ out) {
  const int bid = blockIdx.x, tid = threadIdx.x;
  const int w = tid >> 6, lane = tid & 63;
  const int grp = bid >> 6, gb = bid & 63;
  const bool isA = gb < 32;
  const int l = grp;
  const int g4 = tid >> 7, dd = tid & 127;

  // per-layer weight pointers (bf16)
  const ushortt* Kb  = (const ushortt*)(ws + OFF_KBF)    + (size_t)l*MMEM*HS;
  const ushortt* Vb  = (const ushortt*)(ws + OFF_VBF)    + (size_t)l*MMEM*HS;
  const ushortt* WC  = (const ushortt*)(ws + OFF_WCOMBBF)+ (size_t)l*HS*HS;
  const ushortt* WQ  = (const ushortt*)(ws + OFF_WQTBF)  + (size_t)l*HS*HS;
  const ushortt* CAW = (const ushortt*)(ws + OFF_CAWOBF) + (size_t)l*HS*HS;
  const ushortt* W2  = (const ushortt*)(ws + OFF_W2TBF)  + (size_t)l*FFD*HS;
  const ushortt* F1  = (const ushortt*)(ws + OFF_FFW1BF) + (size_t)l*FFD*HS;
  const ushortt* WG  = (const ushortt*)(ws + OFF_WGCBF)  + (size_t)l*FFD*HS;
  const ushortt* WXb = (const ushortt*)(ws + OFF_WXBF)   + (size_t)l*3*HS*HS;
  const ushortt* WHb = (const ushortt*)(ws + OFF_WHBF)   + (size_t)l*3*HS*HS;
  const float* csag = ws + OFF_CSA + l*HS;
  const float* sqg  = ws + OFF_SQ  + l*HS;
  const float* cbqg = ws + OFF_CBQ + l*HS;
  const float* suv  = ws + OFF_SU  + (size_t)l*FFD;
  const float* cf1  = ws + OFF_CF1 + (size_t)l*FFD;
  const float* cf2  = ws + OFF_CF2 + (size_t)l*FFD;
  // per-layer mutable buffers
  float* hXl  = ws + OFF_HX  + l*HS;
  float* hXp  = ws + OFF_HX  + (l-1)*HS;      // layer l-1's h (grp>0)
  float* z1g  = ws + OFF_Z1  + l*HS;
  float* z02g = ws + OFF_Z02 + (size_t)l*2*1024;
  float* t1g  = ws + OFF_T1  + l*HS;
  float* t2g  = ws + OFF_T2  + l*HS;
  float* YP   = ws + OFF_YP  + (size_t)l*32*HS;
  float* CTXP = ws + OFF_CTXP+ (size_t)l*32*128;
  float* Y2P  = ws + OFF_Y2P + (size_t)l*32*HS;
  float* denS = ws + OFF_DENS+ l*32;
  float* s1s  = ws + OFF_S1S + l*64;
  float* s2s  = ws + OFF_S2S + l*64;
  unsigned* bflags = (unsigned*)(ws + OFF_FLAGS);

  __shared__ float sh_xin[HS], sh_h[HS], sh_vec[HS];
  __shared__ float sh_q[128], sh_p[256], sh_t1[16], sh_t2[16];
  __shared__ float sh_u[64], sh_ff[64], sh_red[24], sh_den[4];

  // ---- one-time register prefetch of all weights ----
  unsigned ph[144];
  if (isA) {
    const int b = gb, head = b >> 3, mseg = b & 7;
#pragma unroll
    for (int rr = 0; rr < 2; ++rr) {
      const ushortt* wc = WC  + (size_t)(b*16 + w*2 + rr)*HS;
      const ushortt* ca = CAW + (size_t)(b*16 + w*2 + rr)*HS;
#pragma unroll
      for (int kk = 0; kk < 4; ++kk) {
        ph[rr*4+kk]      = ldpack(wc + lane + 128*kk, wc + lane + 64 + 128*kk);
        ph[16 + rr*4+kk] = ldpack(ca + lane + 128*kk, ca + lane + 64 + 128*kk);
      }
    }
#pragma unroll
    for (int q = 0; q < 8; ++q)
      ph[8+q] = ldpack(WQ + (size_t)(b*16 + 2*q)*HS + tid,
                       WQ + (size_t)(b*16 + 2*q+1)*HS + tid);
#pragma unroll
    for (int rr = 0; rr < 32; ++rr) {
      const ushortt* kr = Kb + (size_t)(mseg*256 + w*32 + rr)*HS + head*128;
      ph[24+rr] = ldpack(kr + lane, kr + lane + 64);
    }
#pragma unroll
    for (int q = 0; q < 32; ++q)
      ph[56+q] = ldpack(Vb + (size_t)(mseg*256 + g4*64 + 2*q)*HS + head*128 + dd,
                        Vb + (size_t)(mseg*256 + g4*64 + 2*q+1)*HS + head*128 + dd);
#pragma unroll
    for (int q = 0; q < 56; ++q) ph[88+q] = 0;
  } else {
    const int c = gb - 32;
#pragma unroll
    for (int q = 0; q < 8; ++q) {
      const ushortt* b1 = F1 + (size_t)(c*64 + w*8 + q)*HS;
      const ushortt* b2 = WG + (size_t)(c*64 + w*8 + q)*HS;
#pragma unroll
      for (int kk = 0; kk < 4; ++kk) {
        ph[q*4+kk]      = ldpack(b1 + lane + 128*kk, b1 + lane + 64 + 128*kk);
        ph[32 + q*4+kk] = ldpack(b2 + lane + 128*kk, b2 + lane + 64 + 128*kk);
      }
    }
#pragma unroll
    for (int q = 0; q < 32; ++q)
      ph[64+q] = ldpack(W2 + (size_t)(c*64 + 2*q)*HS + tid,
                        W2 + (size_t)(c*64 + 2*q+1)*HS + tid);
#pragma unroll
    for (int rr = 0; rr < 2; ++rr) {
      const ushortt* zx = WXb + (size_t)((1)*HS + c*16 + w*2 + rr)*HS;
      const ushortt* zh = WHb + (size_t)((1)*HS + c*16 + w*2 + rr)*HS;
#pragma unroll
      for (int kk = 0; kk < 4; ++kk) {
        ph[96 + rr*4+kk]  = ldpack(zx + lane + 128*kk, zx + lane + 64 + 128*kk);
        ph[104 + rr*4+kk] = ldpack(zh + lane + 128*kk, zh + lane + 64 + 128*kk);
      }
    }
#pragma unroll
    for (int rr = 0; rr < 4; ++rr) {
      const int rowid = c*32 + w*4 + rr;
      const int g = (rowid < 512) ? 0 : 2, f = rowid & 511;
      const ushortt* zx = WXb + (size_t)(g*HS + f)*HS;
      const ushortt* zh = WHb + (size_t)(g*HS + f)*HS;
#pragma unroll
      for (int kk = 0; kk < 4; ++kk) {
        ph[112 + rr*4+kk] = ldpack(zx + lane + 128*kk, zx + lane + 64 + 128*kk);
        ph[128 + rr*4+kk] = ldpack(zh + lane + 128*kk, zh + lane + 64 + 128*kk);
      }
    }
  }

  float h_reg = 0.f, c_reg = 0.f;   // recurrent state (B blocks, element tid)

  // fused LSTM update for cell (tp, l): B blocks
  auto do_update = [&](int tp) {
    const int j = tid, pz = tp & 1;
    float t2v = ald(t2g + j);
    float z0  = ald(z02g + pz*1024 + j);
    float z2  = ald(z02g + pz*1024 + 512 + j);
    float y2 = 0;
    {
      float yv[16];
#pragma unroll
      for (int c = 0; c < 32; c += 16) {
#pragma unroll
        for (int p = 0; p < 16; ++p) yv[p] = ald(Y2P + (size_t)(c+p)*HS + j);
#pragma unroll
        for (int p = 0; p < 16; ++p) y2 += yv[p];
      }
    }
    slotred32(s2s, sh_red, 16, w, lane);
    __syncthreads();
    float m2 = sh_red[16]*INV512;
    float r2 = rsqrtf(sh_red[17]*INV512 - m2*m2 + 1e-5f);
    float x2 = (t2v-m2)*r2*lnG[(l*3+1)*HS+j] + lnB[(l*3+1)*HS+j];
    float t3 = x2 + y2 + ffB2[l*HS + j];
    float s_ = t3, q_ = t3*t3;
#pragma unroll
    for (int m = 32; m; m >>= 1) { s_ += __shfl_xor(s_, m); q_ += __shfl_xor(q_, m); }
    if (lane == 0) { sh_red[w] = s_; sh_red[8+w] = q_; }
    __syncthreads();
    if (tid == 0) {
      float a = 0, b = 0;
#pragma unroll
      for (int k = 0; k < 8; ++k) { a += sh_red[k]; b += sh_red[8+k]; }
      sh_red[0] = a; sh_red[1] = b;
    }
    __syncthreads();
    float m3 = sh_red[0]*INV512;
    float r3 = rsqrtf(sh_red[1]*INV512 - m3*m3 + 1e-5f);
    float d  = (t3-m3)*r3*lnG[(l*3+2)*HS+j] + lnB[(l*3+2)*HS+j];
    float ft = sigm(c_reg - d);
    float it = sigm(z0);
    float gt = tanhf(z2);
    c_reg = ft*c_reg + it*gt;
    h_reg = tanhf(c_reg);
  };

  for (int W = 0; W < NWIN; ++W) {
    const int V = W - 6*grp;
    if (V >= 0 && V <= 640) {
      const int t = V/5, ph5 = V - t*5;
      if (ph5 == 0 && !isA) {
        const int c = gb - 32;
        if (t > 0) {
          do_update(t-1);
          if (c == 0) {
            ast(hXl + tid, h_reg);
            if (grp == 3) out[(t-1)*HS + tid] = h_reg;
          }
        }
        if (t <= 127) {
          float xin = (grp == 0) ? x[t*HS + tid] : ald(hXp + tid);
          sh_xin[tid] = xin;
          sh_h[tid]   = h_reg;
          __syncthreads();
          // z1 (16 rows)
#pragma unroll
          for (int rr = 0; rr < 2; ++rr) {
            const int row = c*16 + w*2 + rr;
            float acc = 0;
#pragma unroll
            for (int kk = 0; kk < 4; ++kk) {
              unsigned px = ph[96+rr*4+kk], phh = ph[104+rr*4+kk];
              acc += bflo(px)*sh_xin[lane+128*kk] + bfhi(px)*sh_xin[lane+64+128*kk]
                   + bflo(phh)*sh_h[lane+128*kk] + bfhi(phh)*sh_h[lane+64+128*kk];
            }
            acc = wred(acc);
            if (lane == 0)
              ast(z1g + row, acc + bx[(l*3+1)*HS + row] + bh[(l*3+1)*HS + row]);
          }
          // z0/z2 (32 rows)
#pragma unroll
          for (int rr = 0; rr < 4; ++rr) {
            const int rowid = c*32 + w*4 + rr;
            const int g = (rowid < 512) ? 0 : 2, f = rowid & 511;
            float acc = 0;
#pragma unroll
            for (int kk = 0; kk < 4; ++kk) {
              unsigned px = ph[112+rr*4+kk], phh = ph[128+rr*4+kk];
              acc += bflo(px)*sh_xin[lane+128*kk] + bfhi(px)*sh_xin[lane+64+128*kk]
                   + bflo(phh)*sh_h[lane+128*kk] + bfhi(phh)*sh_h[lane+64+128*kk];
            }
            acc = wred(acc);
            if (lane == 0)
              ast(z02g + (t&1)*1024 + (g ? 512 : 0) + f,
                  acc + bx[(l*3+g)*HS + f] + bh[(l*3+g)*HS + f]);
          }
        } else {  // t == 128: final outputs
          if (c == 0) {
            out[TT*HS + grp*HS + tid] = h_reg;
            out[TT*HS + LNUM*HS + grp*HS + tid] = c_reg;
            if (grp == 3) out[127*HS + tid] = h_reg;
          }
        }
      } else if (isA && t <= 127) {
        const int b = gb, head = b >> 3;
        if (ph5 == 1) {
          // t1 + Y partial + s1 slots
          sh_vec[tid] = sigm(ald(z1g + tid));   // f0
          __syncthreads();
#pragma unroll
          for (int rr = 0; rr < 2; ++rr) {
            const int r = w*2 + rr, j = b*16 + r;
            float acc = 0;
#pragma unroll
            for (int kk = 0; kk < 4; ++kk) {
              unsigned pw = ph[rr*4+kk];
              acc += bflo(pw)*sh_vec[lane+128*kk] + bfhi(pw)*sh_vec[lane+64+128*kk];
            }
            acc = wred(acc);
            if (lane == 0) {
              float t1v = sh_vec[j] + acc + csag[j];
              sh_t1[r] = t1v;
              ast(t1g + j, t1v);
            }
          }
          __syncthreads();
          {
            float yl = 0;
#pragma unroll
            for (int q = 0; q < 8; ++q) {
              unsigned pw = ph[8+q];
              yl += sh_t1[2*q]*bflo(pw) + sh_t1[2*q+1]*bfhi(pw);
            }
            ast(YP + (size_t)b*HS + tid, yl);
          }
          if (w == 0 && lane < 16) {
            float v = sh_t1[lane], s_ = v, q_ = v*v;
#pragma unroll
            for (int m = 8; m; m >>= 1) { s_ += __shfl_xor(s_, m); q_ += __shfl_xor(q_, m); }
            if (lane == 0) { ast(s1s + b*2, s_); ast(s1s + b*2 + 1, q_); }
          }
        } else if (ph5 == 2) {
          // attention: q, scores, exp, ctx partial, den slot
          {
            float part = 0;
            float yv[8];
#pragma unroll
            for (int p = 0; p < 8; ++p) yv[p] = ald(YP + (size_t)(g4*8+p)*HS + head*128 + dd);
#pragma unroll
            for (int p = 0; p < 8; ++p) part += yv[p];
            sh_vec[tid] = part;
          }
          slotred32(s1s, sh_red, 18, w, lane);
          __syncthreads();
          if (tid < 128) {
            float Ysum = sh_vec[tid] + sh_vec[128+tid] + sh_vec[256+tid] + sh_vec[384+tid];
            float m1 = sh_red[18]*INV512;
            float r1 = rsqrtf(sh_red[19]*INV512 - m1*m1 + 1e-5f);
            int f = head*128 + tid;
            sh_q[tid] = r1*(Ysum - m1*sqg[f]) + cbqg[f];
          }
          __syncthreads();
#pragma unroll
          for (int rr = 0; rr < 32; ++rr) {
            unsigned pw = ph[24+rr];
            float sc = sh_q[lane]*bflo(pw) + sh_q[lane+64]*bfhi(pw);
            sc = wred(sc);
            if (lane == 0) sh_p[w*32+rr] = __expf(sc * QSCALE);
          }
          __syncthreads();
          {
            float acc = 0;
#pragma unroll
            for (int q = 0; q < 32; ++q) {
              unsigned pw = ph[56+q];
              acc += sh_p[g4*64 + 2*q]*bflo(pw) + sh_p[g4*64 + 2*q+1]*bfhi(pw);
            }
            sh_vec[tid] = acc;
          }
          if (w == 0) {
            float v = sh_p[lane] + sh_p[64+lane] + sh_p[128+lane] + sh_p[192+lane];
            v = wred(v);
            if (lane == 0) ast(denS + b, v);
          }
          __syncthreads();
          if (tid < 128) {
            float tot = sh_vec[tid] + sh_vec[128+tid] + sh_vec[256+tid] + sh_vec[384+tid];
            ast(CTXP + (size_t)b*128 + tid, tot);
          }
        } else if (ph5 == 3) {
          // t2 + s2 slots
          slotred32(s1s, sh_red, 18, w, lane);
          if (w == 4) {
            float v = (lane < 32) ? ald(denS + lane) : 0.f;
#pragma unroll
            for (int m = 4; m; m >>= 1) v += __shfl_xor(v, m);
            if ((lane & 7) == 0 && lane < 32) sh_den[lane >> 3] = v;
          }
          __syncthreads();
          {
            const int hh = tid >> 7;
            float cn = 0;
            float cv[8];
#pragma unroll
            for (int p = 0; p < 8; ++p) cv[p] = ald(CTXP + (size_t)(hh*8+p)*128 + dd);
#pragma unroll
            for (int p = 0; p < 8; ++p) cn += cv[p];
            sh_vec[tid] = cn / sh_den[hh];
          }
          __syncthreads();
          const float m1 = sh_red[18]*INV512;
          const float r1 = rsqrtf(sh_red[19]*INV512 - m1*m1 + 1e-5f);
#pragma unroll
          for (int rr = 0; rr < 2; ++rr) {
            const int r = w*2 + rr, j = b*16 + r;
            float a2 = 0;
#pragma unroll
            for (int kk = 0; kk < 4; ++kk) {
              unsigned pw = ph[16+rr*4+kk];
              a2 += bflo(pw)*sh_vec[lane+128*kk] + bfhi(pw)*sh_vec[lane+64+128*kk];
            }
            a2 = wred(a2);
            if (lane == 0) {
              float x1 = (sh_t1[r]-m1)*r1*lnG[(l*3)*HS + j] + lnB[(l*3)*HS + j];
              float t2v = x1 + a2 + caBo[l*HS + j];
              ast(t2g + j, t2v);
              sh_t2[r] = t2v;
            }
          }
          __syncthreads();
          if (w == 0 && lane < 16) {
            float v = sh_t2[lane], s_ = v, q_ = v*v;
#pragma unroll
            for (int m = 8; m; m >>= 1) { s_ += __shfl_xor(s_, m); q_ += __shfl_xor(q_, m); }
            if (lane == 0) { ast(s2s + b*2, s_); ast(s2s + b*2 + 1, q_); }
          }
        }
      } else if (!isA && t <= 127) {
        const int c = gb - 32;
        if (ph5 == 3) {
          // ff matvec u = W1@(x1*g2) + WGC@ctxn
          float t1v = ald(t1g + tid);
          slotred32(s1s, sh_red, 18, w, lane);
          if (w == 4) {
            float v = (lane < 32) ? ald(denS + lane) : 0.f;
#pragma unroll
            for (int m = 4; m; m >>= 1) v += __shfl_xor(v, m);
            if ((lane & 7) == 0 && lane < 32) sh_den[lane >> 3] = v;
          }
          __syncthreads();
          {
            const float m1 = sh_red[18]*INV512;
            const float r1 = rsqrtf(sh_red[19]*INV512 - m1*m1 + 1e-5f);
            sh_xin[tid] = ((t1v - m1)*r1*lnG[(l*3)*HS + tid] + lnB[(l*3)*HS + tid])
                          * lnG[(l*3+1)*HS + tid];
          }
          {
            const int hh = tid >> 7;
            float cn = 0;
            float cv[8];
#pragma unroll
            for (int p = 0; p < 8; ++p) cv[p] = ald(CTXP + (size_t)(hh*8+p)*128 + dd);
#pragma unroll
            for (int p = 0; p < 8; ++p) cn += cv[p];
            sh_vec[tid] = cn / sh_den[hh];
          }
          __syncthreads();
#pragma unroll
          for (int q = 0; q < 8; ++q) {
            float acc = 0;
#pragma unroll
            for (int kk = 0; kk < 4; ++kk) {
              unsigned pw1 = ph[q*4+kk], pw2 = ph[32+q*4+kk];
              acc += bflo(pw1)*sh_xin[lane+128*kk] + bfhi(pw1)*sh_xin[lane+64+128*kk]
                   + bflo(pw2)*sh_vec[lane+128*kk] + bfhi(pw2)*sh_vec[lane+64+128*kk];
            }
            acc = wred(acc);
            if (lane == 0) sh_u[w*8+q] = acc;
          }
        } else if (ph5 == 4) {
          // ff finish + Y2 partial plane
          slotred32(s2s, sh_red, 16, w, lane);
          __syncthreads();
          const float m2 = sh_red[16]*INV512;
          const float r2 = rsqrtf(sh_red[17]*INV512 - m2*m2 + 1e-5f);
          if (lane == 0) {
#pragma unroll
            for (int q = 0; q < 8; ++q) {
              const int row = c*64 + w*8 + q;
              sh_ff[w*8+q] = fmaxf(r2*(sh_u[w*8+q] + cf1[row] - m2*suv[row]) + cf2[row], 0.f);
            }
          }
          __syncthreads();
          {
            float yl = 0;
#pragma unroll
            for (int q = 0; q < 32; ++q) {
              unsigned pw = ph[64+q];
              yl += sh_ff[2*q]*bflo(pw) + sh_ff[2*q+1]*bfhi(pw);
            }
            ast(Y2P + (size_t)c*HS + tid, yl);
          }
        }
      }
    }
    gridbar(bflags, (unsigned)(W+1));
  }
}

// ---------------- host launcher ----------------
extern "C" void kernel_launch(void* const* d_in, const int* in_sizes, int n_in,
                              void* d_out, int out_size, void* d_ws, size_t ws_size,
                              hipStream_t stream) {
  const float* x      = (const float*)d_in[0];
  const float* hist   = (const float*)d_in[1];
  const float* Wx     = (const float*)d_in[2];
  const float* bx     = (const float*)d_in[3];
  const float* Wh     = (const float*)d_in[4];
  const float* bh     = (const float*)d_in[5];
  const float* saWin  = (const float*)d_in[6];
  const float* saBin  = (const float*)d_in[7];
  const float* saWo   = (const float*)d_in[8];
  const float* saBo   = (const float*)d_in[9];
  const float* caWin  = (const float*)d_in[10];
  const float* caBin  = (const float*)d_in[11];
  const float* caWo   = (const float*)d_in[12];
  const float* caBo   = (const float*)d_in[13];
  const float* ffW1   = (const float*)d_in[14];
  const float* ffB1   = (const float*)d_in[15];
  const float* ffW2   = (const float*)d_in[16];
  const float* ffB2   = (const float*)d_in[17];
  const float* lnG    = (const float*)d_in[18];
  const float* lnB    = (const float*)d_in[19];
  float* ws  = (float*)d_ws;
  float* out = (float*)d_out;

  hipMemsetAsync((char*)d_ws + OFF_STATE*sizeof(float), 0,
                 (WS_TOTAL - OFF_STATE)*sizeof(float), stream);

  kv_gemm<<<dim3(MMEM/64, HS/64, LNUM), 256, 0, stream>>>(
      hist, caWin, caBin, (ushortt*)(ws + OFF_KBF), HS);
  kv_gemm<<<dim3(MMEM/64, HS/64, LNUM), 256, 0, stream>>>(
      hist, caWin, caBin, (ushortt*)(ws + OFF_VBF), 2*HS);
  wcomb_gemm<<<dim3(HS/64, HS/64, LNUM), 256, 0, stream>>>(
      saWo, saWin, (ushortt*)(ws + OFF_WCOMBBF));
  wgc_gemm<<<dim3(FFD/64, HS/64, LNUM), 256, 0, stream>>>(
      ffW1, lnG, caWo, (ushortt*)(ws + OFF_WGCBF));
  csa_kernel<<<(LNUM*HS)/4, 256, 0, stream>>>(saWo, saBin, saBo, ws + OFF_CSA);
  transpose_scale_bf<<<dim3(HS/32, HS/32, LNUM), 256, 0, stream>>>(
      caWin, (size_t)(3*HS)*HS, HS, HS, lnG, (size_t)(3*HS),
      (ushortt*)(ws + OFF_WQTBF), (size_t)HS*HS);
  sqcbq_kernel<<<(LNUM*HS)/4, 256, 0, stream>>>(caWin, caBin, lnG, lnB, ws + OFF_SQ, ws + OFF_CBQ);
  transpose_scale_bf<<<dim3(FFD/32, HS/32, LNUM), 256, 0, stream>>>(
      ffW2, (size_t)HS*FFD, HS, FFD, nullptr, 0,
      (ushortt*)(ws + OFF_W2TBF), (size_t)FFD*HS);
  bf16_copy<<<2048, 256, 0, stream>>>(ffW1, (ushortt*)(ws + OFF_FFW1BF), (size_t)LNUM*FFD*HS);
  bf16_copy<<<1024, 256, 0, stream>>>(caWo, (ushortt*)(ws + OFF_CAWOBF), (size_t)LNUM*HS*HS);
  bf16_copy<<<2048, 256, 0, stream>>>(Wx, (ushortt*)(ws + OFF_WXBF), (size_t)LNUM*3*HS*HS);
  bf16_copy<<<2048, 256, 0, stream>>>(Wh, (ushortt*)(ws + OFF_WHBF), (size_t)LNUM*3*HS*HS);
  ffvec_kernel<<<(LNUM*FFD)/4, 256, 0, stream>>>(ffW1, ffB1, caBo, lnG, lnB,
      ws + OFF_SU, ws + OFF_CF1, ws + OFF_CF2);

  seq_kernel<<<NB, NT, 0, stream>>>(x, bx, bh, caBo, ffB2, lnG, lnB, ws, out);
}